// Round 1
// baseline (6805.862 us; speedup 1.0000x reference)
//
#include <hip/hip_runtime.h>

#define N_NODES 50000
#define N_EDGES 800000
#define D 128
#define NUM_GRAPHS 128

// ---------------------------------------------------------------------------
// agg[dst] += h[src]  — one 32-thread group per edge, float4 per thread
// ---------------------------------------------------------------------------
__global__ __launch_bounds__(256) void scatter_kernel(
    const float4* __restrict__ H, const int* __restrict__ src,
    const int* __restrict__ dst, float* __restrict__ agg)
{
    int gid = blockIdx.x * 256 + threadIdx.x;
    if (gid >= N_EDGES * 32) return;
    int e  = gid >> 5;
    int c4 = gid & 31;
    int s = src[e];
    int d = dst[e];
    float4 v = H[s * 32 + c4];
    float* a = agg + d * D + c4 * 4;
    atomicAdd(a + 0, v.x);
    atomicAdd(a + 1, v.y);
    atomicAdd(a + 2, v.z);
    atomicAdd(a + 3, v.w);
}

// ---------------------------------------------------------------------------
// out = [ReLU]( in @ W + bias ),  in = A (+ (1+eps)*Hin if Hin != null)
// Optional per-column sum / sumsq accumulation (for BatchNorm) on out values.
// Block: 256 threads -> 64 rows x 128 cols tile. Each thread: 8 rows x 4 cols.
// LDS: A tile 32KB + W k-chunk 32KB + 1KB stats  => 2 blocks/CU.
// NOTE: out may alias A (each block stages its rows to LDS before writing).
// ---------------------------------------------------------------------------
__global__ __launch_bounds__(256) void mlp_kernel(
    const float* __restrict__ A,
    const float* __restrict__ Hin,
    const float* __restrict__ epsp,
    const float* __restrict__ W,
    const float* __restrict__ bias,
    float* __restrict__ out,
    float* __restrict__ statsSum,
    float* __restrict__ statsSq,
    int relu, int M)
{
    __shared__ float Alds[64 * 128];
    __shared__ float Wlds[64 * 128];
    __shared__ float ssum[128];
    __shared__ float ssq[128];

    const int tid  = threadIdx.x;
    const int tx   = tid & 31;   // col4 index: cols 4*tx .. 4*tx+3
    const int ty   = tid >> 5;   // row group: rows ty*8 .. ty*8+7
    const int row0 = blockIdx.x * 64;

    float scale = 0.0f;
    if (Hin) scale = 1.0f + *epsp;

    // ---- stage input tile (fused (1+eps)*h + agg) ----
    const float4* A4 = (const float4*)A;
    const float4* H4 = (const float4*)Hin;
    float4* Alds4 = (float4*)Alds;
    #pragma unroll
    for (int i = 0; i < 8; ++i) {
        int fi = i * 256 + tid;          // 0..2047 float4s
        int r  = fi >> 5;
        int c  = fi & 31;
        int gr = row0 + r;
        float4 v = make_float4(0.f, 0.f, 0.f, 0.f);
        if (gr < M) {
            v = A4[gr * 32 + c];
            if (Hin) {
                float4 hv = H4[gr * 32 + c];
                v.x += scale * hv.x; v.y += scale * hv.y;
                v.z += scale * hv.z; v.w += scale * hv.w;
            }
        }
        Alds4[fi] = v;
    }

    float4 acc[8];
    #pragma unroll
    for (int rr = 0; rr < 8; ++rr) acc[rr] = make_float4(0.f, 0.f, 0.f, 0.f);

    const float4* W4 = (const float4*)W;
    float4* Wlds4 = (float4*)Wlds;

    for (int kc = 0; kc < 2; ++kc) {
        __syncthreads();               // A staged (iter0) / Wlds free (iter1)
        #pragma unroll
        for (int i = 0; i < 8; ++i) {
            int fi = i * 256 + tid;
            Wlds4[fi] = W4[kc * 2048 + fi];   // 64 k-rows x 32 float4
        }
        __syncthreads();
        #pragma unroll
        for (int kq = 0; kq < 16; ++kq) {
            float4 w0 = Wlds4[(kq * 4 + 0) * 32 + tx];
            float4 w1 = Wlds4[(kq * 4 + 1) * 32 + tx];
            float4 w2 = Wlds4[(kq * 4 + 2) * 32 + tx];
            float4 w3 = Wlds4[(kq * 4 + 3) * 32 + tx];
            #pragma unroll
            for (int rr = 0; rr < 8; ++rr) {
                float4 a = Alds4[(ty * 8 + rr) * 32 + kc * 16 + kq];
                acc[rr].x += a.x * w0.x + a.y * w1.x + a.z * w2.x + a.w * w3.x;
                acc[rr].y += a.x * w0.y + a.y * w1.y + a.z * w2.y + a.w * w3.y;
                acc[rr].z += a.x * w0.z + a.y * w1.z + a.z * w2.z + a.w * w3.z;
                acc[rr].w += a.x * w0.w + a.y * w1.w + a.z * w2.w + a.w * w3.w;
            }
        }
    }

    // ---- epilogue: bias, relu, store, optional BN stats ----
    const float4 b4 = ((const float4*)bias)[tx];
    const bool doStats = (statsSum != nullptr);
    if (doStats && tid < 128) { ssum[tid] = 0.f; ssq[tid] = 0.f; }
    __syncthreads();

    float4 locS = make_float4(0.f, 0.f, 0.f, 0.f);
    float4 locQ = make_float4(0.f, 0.f, 0.f, 0.f);
    float4* out4 = (float4*)out;
    #pragma unroll
    for (int rr = 0; rr < 8; ++rr) {
        int gr = row0 + ty * 8 + rr;
        if (gr >= M) continue;
        float4 v;
        v.x = acc[rr].x + b4.x;
        v.y = acc[rr].y + b4.y;
        v.z = acc[rr].z + b4.z;
        v.w = acc[rr].w + b4.w;
        if (relu) {
            v.x = fmaxf(v.x, 0.f); v.y = fmaxf(v.y, 0.f);
            v.z = fmaxf(v.z, 0.f); v.w = fmaxf(v.w, 0.f);
        }
        out4[gr * 32 + tx] = v;
        if (doStats) {
            locS.x += v.x; locS.y += v.y; locS.z += v.z; locS.w += v.w;
            locQ.x += v.x * v.x; locQ.y += v.y * v.y;
            locQ.z += v.z * v.z; locQ.w += v.w * v.w;
        }
    }
    if (doStats) {
        atomicAdd(&ssum[4 * tx + 0], locS.x);
        atomicAdd(&ssum[4 * tx + 1], locS.y);
        atomicAdd(&ssum[4 * tx + 2], locS.z);
        atomicAdd(&ssum[4 * tx + 3], locS.w);
        atomicAdd(&ssq[4 * tx + 0], locQ.x);
        atomicAdd(&ssq[4 * tx + 1], locQ.y);
        atomicAdd(&ssq[4 * tx + 2], locQ.z);
        atomicAdd(&ssq[4 * tx + 3], locQ.w);
        __syncthreads();
        if (tid < 128) {
            atomicAdd(&statsSum[tid], ssum[tid]);
            atomicAdd(&statsSq[tid],  ssq[tid]);
        }
    }
}

// ---------------------------------------------------------------------------
// In-place BatchNorm (batch statistics) + ReLU
// ---------------------------------------------------------------------------
__global__ __launch_bounds__(256) void bn_kernel(
    float4* __restrict__ Z, const float* __restrict__ sum,
    const float* __restrict__ sq, const float4* __restrict__ gamma,
    const float4* __restrict__ beta, int M)
{
    int gid = blockIdx.x * 256 + threadIdx.x;
    if (gid >= M * 32) return;
    int c4 = gid & 31;
    float4 s = ((const float4*)sum)[c4];
    float4 q = ((const float4*)sq)[c4];
    float invM = 1.0f / (float)M;
    float4 mean, inv;
    mean.x = s.x * invM; mean.y = s.y * invM;
    mean.z = s.z * invM; mean.w = s.w * invM;
    inv.x = rsqrtf(q.x * invM - mean.x * mean.x + 1e-5f);
    inv.y = rsqrtf(q.y * invM - mean.y * mean.y + 1e-5f);
    inv.z = rsqrtf(q.z * invM - mean.z * mean.z + 1e-5f);
    inv.w = rsqrtf(q.w * invM - mean.w * mean.w + 1e-5f);
    float4 g = gamma[c4];
    float4 b = beta[c4];
    float4 v = Z[gid];
    v.x = fmaxf((v.x - mean.x) * inv.x * g.x + b.x, 0.f);
    v.y = fmaxf((v.y - mean.y) * inv.y * g.y + b.y, 0.f);
    v.z = fmaxf((v.z - mean.z) * inv.z * g.z + b.z, 0.f);
    v.w = fmaxf((v.w - mean.w) * inv.w * g.w + b.w, 0.f);
    Z[gid] = v;
}

// ---------------------------------------------------------------------------
// global_add_pool: out[batch[n]] += h[n]
// ---------------------------------------------------------------------------
__global__ __launch_bounds__(256) void pool_kernel(
    const float4* __restrict__ H, const int* __restrict__ batch,
    float* __restrict__ out)
{
    int gid = blockIdx.x * 256 + threadIdx.x;
    if (gid >= N_NODES * 32) return;
    int n  = gid >> 5;
    int c4 = gid & 31;
    int g = batch[n];
    float4 v = H[n * 32 + c4];
    float* o = out + g * D + c4 * 4;
    atomicAdd(o + 0, v.x);
    atomicAdd(o + 1, v.y);
    atomicAdd(o + 2, v.z);
    atomicAdd(o + 3, v.w);
}

extern "C" void kernel_launch(void* const* d_in, const int* in_sizes, int n_in,
                              void* d_out, int out_size, void* d_ws, size_t ws_size,
                              hipStream_t stream)
{
    const float* x     = (const float*)d_in[0];
    const int*   ei    = (const int*)d_in[1];
    const int*   batch = (const int*)d_in[2];
    const float* W1    = (const float*)d_in[3];
    const float* b1    = (const float*)d_in[4];
    const float* W2    = (const float*)d_in[5];
    const float* b2    = (const float*)d_in[6];
    const float* eps   = (const float*)d_in[7];
    const float* gamma = (const float*)d_in[8];
    const float* beta  = (const float*)d_in[9];
    float* out = (float*)d_out;

    float* agg      = (float*)d_ws;                 // [N,D]; z1 aliases this
    float* Hbuf     = agg + (size_t)N_NODES * D;    // [N,D]
    float* statsSum = Hbuf + (size_t)N_NODES * D;   // [D]
    float* statsSq  = statsSum + D;                 // [D]

    const int* src = ei;
    const int* dst = ei + N_EDGES;

    dim3 blk(256);
    const int gemmBlocks    = (N_NODES + 63) / 64;       // 782
    const int scatterBlocks = N_EDGES * 32 / 256;        // 100000
    const int elemBlocks    = N_NODES * 32 / 256;        // 6250

    for (int layer = 0; layer < 4; ++layer) {
        const float* hin = (layer == 0) ? x : Hbuf;
        hipMemsetAsync(agg, 0, (size_t)N_NODES * D * sizeof(float), stream);
        scatter_kernel<<<scatterBlocks, blk, 0, stream>>>(
            (const float4*)hin, src, dst, agg);
        // z1 = ReLU(((1+eps)*h + agg) @ W1 + b1)   (written in-place into agg)
        mlp_kernel<<<gemmBlocks, blk, 0, stream>>>(
            agg, hin, eps + layer, W1 + (size_t)layer * D * D,
            b1 + (size_t)layer * D, agg, nullptr, nullptr, 1, N_NODES);
        const bool bn = (layer < 3);
        if (bn) hipMemsetAsync(statsSum, 0, 2 * D * sizeof(float), stream);
        // z2 = z1 @ W2 + b2  -> Hbuf  (+ column stats for BN)
        mlp_kernel<<<gemmBlocks, blk, 0, stream>>>(
            agg, nullptr, nullptr, W2 + (size_t)layer * D * D,
            b2 + (size_t)layer * D, Hbuf,
            bn ? statsSum : nullptr, bn ? statsSq : nullptr, 0, N_NODES);
        if (bn) bn_kernel<<<elemBlocks, blk, 0, stream>>>(
            (float4*)Hbuf, statsSum, statsSq,
            (const float4*)(gamma + (size_t)layer * D),
            (const float4*)(beta + (size_t)layer * D), N_NODES);
    }

    hipMemsetAsync(out, 0, (size_t)NUM_GRAPHS * D * sizeof(float), stream);
    pool_kernel<<<elemBlocks, blk, 0, stream>>>(
        (const float4*)Hbuf, batch, out);
}

// Round 2
// 1849.520 us; speedup vs baseline: 3.6798x; 3.6798x over previous
//
#include <hip/hip_runtime.h>

#define N_NODES 50000
#define N_EDGES 800000
#define D 128
#define NUM_GRAPHS 128

// ===========================================================================
// CSR build (per launch — edge list is re-poisoned-safe input, same each call)
// ===========================================================================
__global__ __launch_bounds__(256) void hist_kernel(
    const int* __restrict__ dst, int* __restrict__ deg)
{
    int e = blockIdx.x * 256 + threadIdx.x;
    if (e < N_EDGES) atomicAdd(&deg[dst[e]], 1);
}

// Single-workgroup chunked inclusive scan: row_ptr[n+1] = sum deg[0..n]
__global__ __launch_bounds__(1024) void scan_kernel(
    const int* __restrict__ deg, int* __restrict__ row_ptr)
{
    __shared__ int buf[1024];
    __shared__ int carry;
    int tid = threadIdx.x;
    if (tid == 0) { carry = 0; row_ptr[0] = 0; }
    __syncthreads();
    for (int base = 0; base < N_NODES; base += 1024) {
        int v = (base + tid < N_NODES) ? deg[base + tid] : 0;
        buf[tid] = v;
        __syncthreads();
        #pragma unroll
        for (int off = 1; off < 1024; off <<= 1) {
            int t = (tid >= off) ? buf[tid - off] : 0;
            __syncthreads();
            buf[tid] += t;
            __syncthreads();
        }
        int incl = buf[tid] + carry;
        if (base + tid < N_NODES) row_ptr[base + tid + 1] = incl;
        __syncthreads();
        if (tid == 1023) carry = incl;
        __syncthreads();
    }
}

__global__ __launch_bounds__(256) void fill_kernel(
    const int* __restrict__ src, const int* __restrict__ dst,
    const int* __restrict__ row_ptr, int* __restrict__ cursor,
    int* __restrict__ csr_src)
{
    int e = blockIdx.x * 256 + threadIdx.x;
    if (e >= N_EDGES) return;
    int d = dst[e];
    int pos = atomicAdd(&cursor[d], 1);
    csr_src[row_ptr[d] + pos] = src[e];
}

// ===========================================================================
// agg[n] = sum_{e in CSR(n)} h[src[e]]  — 32 lanes per node, float4/lane
// ===========================================================================
__global__ __launch_bounds__(256) void gather_kernel(
    const float4* __restrict__ H, const int* __restrict__ row_ptr,
    const int* __restrict__ csr_src, float4* __restrict__ agg)
{
    int node = blockIdx.x * 8 + (threadIdx.x >> 5);
    if (node >= N_NODES) return;
    int lane = threadIdx.x & 31;
    int beg = row_ptr[node];
    int end = row_ptr[node + 1];
    float4 acc = make_float4(0.f, 0.f, 0.f, 0.f);
    for (int i = beg; i < end; ++i) {
        int s = csr_src[i];
        float4 v = H[s * 32 + lane];
        acc.x += v.x; acc.y += v.y; acc.z += v.z; acc.w += v.w;
    }
    agg[node * 32 + lane] = acc;
}

// ===========================================================================
// out = [ReLU]( in @ W + bias ),  in = A (+ (1+eps)*Hin if Hin != null)
// Optional per-column sum / sumsq accumulation (for BatchNorm) on out values.
// Block: 256 threads -> 64 rows x 128 cols tile. Each thread: 8 rows x 4 cols.
// NOTE: out may alias A (each block stages its rows to LDS before writing).
// ===========================================================================
__global__ __launch_bounds__(256) void mlp_kernel(
    const float* __restrict__ A,
    const float* __restrict__ Hin,
    const float* __restrict__ epsp,
    const float* __restrict__ W,
    const float* __restrict__ bias,
    float* __restrict__ out,
    float* __restrict__ statsSum,
    float* __restrict__ statsSq,
    int relu, int M)
{
    __shared__ float Alds[64 * 128];
    __shared__ float Wlds[64 * 128];
    __shared__ float ssum[128];
    __shared__ float ssq[128];

    const int tid  = threadIdx.x;
    const int tx   = tid & 31;   // col4 index: cols 4*tx .. 4*tx+3
    const int ty   = tid >> 5;   // row group: rows ty*8 .. ty*8+7
    const int row0 = blockIdx.x * 64;

    float scale = 0.0f;
    if (Hin) scale = 1.0f + *epsp;

    const float4* A4 = (const float4*)A;
    const float4* H4 = (const float4*)Hin;
    float4* Alds4 = (float4*)Alds;
    #pragma unroll
    for (int i = 0; i < 8; ++i) {
        int fi = i * 256 + tid;          // 0..2047 float4s
        int r  = fi >> 5;
        int c  = fi & 31;
        int gr = row0 + r;
        float4 v = make_float4(0.f, 0.f, 0.f, 0.f);
        if (gr < M) {
            v = A4[gr * 32 + c];
            if (Hin) {
                float4 hv = H4[gr * 32 + c];
                v.x += scale * hv.x; v.y += scale * hv.y;
                v.z += scale * hv.z; v.w += scale * hv.w;
            }
        }
        Alds4[fi] = v;
    }

    float4 acc[8];
    #pragma unroll
    for (int rr = 0; rr < 8; ++rr) acc[rr] = make_float4(0.f, 0.f, 0.f, 0.f);

    const float4* W4 = (const float4*)W;
    float4* Wlds4 = (float4*)Wlds;

    for (int kc = 0; kc < 2; ++kc) {
        __syncthreads();
        #pragma unroll
        for (int i = 0; i < 8; ++i) {
            int fi = i * 256 + tid;
            Wlds4[fi] = W4[kc * 2048 + fi];   // 64 k-rows x 32 float4
        }
        __syncthreads();
        #pragma unroll
        for (int kq = 0; kq < 16; ++kq) {
            float4 w0 = Wlds4[(kq * 4 + 0) * 32 + tx];
            float4 w1 = Wlds4[(kq * 4 + 1) * 32 + tx];
            float4 w2 = Wlds4[(kq * 4 + 2) * 32 + tx];
            float4 w3 = Wlds4[(kq * 4 + 3) * 32 + tx];
            #pragma unroll
            for (int rr = 0; rr < 8; ++rr) {
                float4 a = Alds4[(ty * 8 + rr) * 32 + kc * 16 + kq];
                acc[rr].x += a.x * w0.x + a.y * w1.x + a.z * w2.x + a.w * w3.x;
                acc[rr].y += a.x * w0.y + a.y * w1.y + a.z * w2.y + a.w * w3.y;
                acc[rr].z += a.x * w0.z + a.y * w1.z + a.z * w2.z + a.w * w3.z;
                acc[rr].w += a.x * w0.w + a.y * w1.w + a.z * w2.w + a.w * w3.w;
            }
        }
    }

    const float4 b4 = ((const float4*)bias)[tx];
    const bool doStats = (statsSum != nullptr);
    if (doStats && tid < 128) { ssum[tid] = 0.f; ssq[tid] = 0.f; }
    __syncthreads();

    float4 locS = make_float4(0.f, 0.f, 0.f, 0.f);
    float4 locQ = make_float4(0.f, 0.f, 0.f, 0.f);
    float4* out4 = (float4*)out;
    #pragma unroll
    for (int rr = 0; rr < 8; ++rr) {
        int gr = row0 + ty * 8 + rr;
        if (gr >= M) continue;
        float4 v;
        v.x = acc[rr].x + b4.x;
        v.y = acc[rr].y + b4.y;
        v.z = acc[rr].z + b4.z;
        v.w = acc[rr].w + b4.w;
        if (relu) {
            v.x = fmaxf(v.x, 0.f); v.y = fmaxf(v.y, 0.f);
            v.z = fmaxf(v.z, 0.f); v.w = fmaxf(v.w, 0.f);
        }
        out4[gr * 32 + tx] = v;
        if (doStats) {
            locS.x += v.x; locS.y += v.y; locS.z += v.z; locS.w += v.w;
            locQ.x += v.x * v.x; locQ.y += v.y * v.y;
            locQ.z += v.z * v.z; locQ.w += v.w * v.w;
        }
    }
    if (doStats) {
        atomicAdd(&ssum[4 * tx + 0], locS.x);
        atomicAdd(&ssum[4 * tx + 1], locS.y);
        atomicAdd(&ssum[4 * tx + 2], locS.z);
        atomicAdd(&ssum[4 * tx + 3], locS.w);
        atomicAdd(&ssq[4 * tx + 0], locQ.x);
        atomicAdd(&ssq[4 * tx + 1], locQ.y);
        atomicAdd(&ssq[4 * tx + 2], locQ.z);
        atomicAdd(&ssq[4 * tx + 3], locQ.w);
        __syncthreads();
        if (tid < 128) {
            atomicAdd(&statsSum[tid], ssum[tid]);
            atomicAdd(&statsSq[tid],  ssq[tid]);
        }
    }
}

// ===========================================================================
// In-place BatchNorm (batch statistics) + ReLU
// ===========================================================================
__global__ __launch_bounds__(256) void bn_kernel(
    float4* __restrict__ Z, const float* __restrict__ sum,
    const float* __restrict__ sq, const float4* __restrict__ gamma,
    const float4* __restrict__ beta, int M)
{
    int gid = blockIdx.x * 256 + threadIdx.x;
    if (gid >= M * 32) return;
    int c4 = gid & 31;
    float4 s = ((const float4*)sum)[c4];
    float4 q = ((const float4*)sq)[c4];
    float invM = 1.0f / (float)M;
    float4 mean, inv;
    mean.x = s.x * invM; mean.y = s.y * invM;
    mean.z = s.z * invM; mean.w = s.w * invM;
    inv.x = rsqrtf(q.x * invM - mean.x * mean.x + 1e-5f);
    inv.y = rsqrtf(q.y * invM - mean.y * mean.y + 1e-5f);
    inv.z = rsqrtf(q.z * invM - mean.z * mean.z + 1e-5f);
    inv.w = rsqrtf(q.w * invM - mean.w * mean.w + 1e-5f);
    float4 g = gamma[c4];
    float4 b = beta[c4];
    float4 v = Z[gid];
    v.x = fmaxf((v.x - mean.x) * inv.x * g.x + b.x, 0.f);
    v.y = fmaxf((v.y - mean.y) * inv.y * g.y + b.y, 0.f);
    v.z = fmaxf((v.z - mean.z) * inv.z * g.z + b.z, 0.f);
    v.w = fmaxf((v.w - mean.w) * inv.w * g.w + b.w, 0.f);
    Z[gid] = v;
}

// ===========================================================================
// global_add_pool: out[batch[n]] += h[n]
// ===========================================================================
__global__ __launch_bounds__(256) void pool_kernel(
    const float4* __restrict__ H, const int* __restrict__ batch,
    float* __restrict__ out)
{
    int gid = blockIdx.x * 256 + threadIdx.x;
    if (gid >= N_NODES * 32) return;
    int n  = gid >> 5;
    int c4 = gid & 31;
    int g = batch[n];
    float4 v = H[n * 32 + c4];
    float* o = out + g * D + c4 * 4;
    atomicAdd(o + 0, v.x);
    atomicAdd(o + 1, v.y);
    atomicAdd(o + 2, v.z);
    atomicAdd(o + 3, v.w);
}

extern "C" void kernel_launch(void* const* d_in, const int* in_sizes, int n_in,
                              void* d_out, int out_size, void* d_ws, size_t ws_size,
                              hipStream_t stream)
{
    const float* x     = (const float*)d_in[0];
    const int*   ei    = (const int*)d_in[1];
    const int*   batch = (const int*)d_in[2];
    const float* W1    = (const float*)d_in[3];
    const float* b1    = (const float*)d_in[4];
    const float* W2    = (const float*)d_in[5];
    const float* b2    = (const float*)d_in[6];
    const float* eps   = (const float*)d_in[7];
    const float* gamma = (const float*)d_in[8];
    const float* beta  = (const float*)d_in[9];
    float* out = (float*)d_out;

    // ---- workspace layout ----
    float* agg      = (float*)d_ws;                 // [N,D]; z1 aliases this
    float* Hbuf     = agg + (size_t)N_NODES * D;    // [N,D]
    float* statsSum = Hbuf + (size_t)N_NODES * D;   // [D]
    float* statsSq  = statsSum + D;                 // [D]
    int*   deg      = (int*)(statsSq + D);          // [N]
    int*   row_ptr  = deg + N_NODES;                // [N+1]
    int*   cursor   = row_ptr + N_NODES + 1;        // [N]
    int*   csr_src  = cursor + N_NODES;             // [E]

    const int* src = ei;
    const int* dst = ei + N_EDGES;

    dim3 blk(256);
    const int gemmBlocks   = (N_NODES + 63) / 64;        // 782
    const int edgeBlocks   = (N_EDGES + 255) / 256;      // 3125
    const int elemBlocks   = N_NODES * 32 / 256;         // 6250
    const int gatherBlocks = (N_NODES + 7) / 8;          // 6250

    // ---- build CSR (edges -> per-dst adjacency) ----
    hipMemsetAsync(deg, 0, (size_t)(2 * N_NODES) * sizeof(int), stream); // deg+? just deg
    hipMemsetAsync(cursor, 0, (size_t)N_NODES * sizeof(int), stream);
    hist_kernel<<<edgeBlocks, blk, 0, stream>>>(dst, deg);
    scan_kernel<<<1, 1024, 0, stream>>>(deg, row_ptr);
    fill_kernel<<<edgeBlocks, blk, 0, stream>>>(src, dst, row_ptr, cursor, csr_src);

    for (int layer = 0; layer < 4; ++layer) {
        const float* hin = (layer == 0) ? x : Hbuf;
        gather_kernel<<<gatherBlocks, blk, 0, stream>>>(
            (const float4*)hin, row_ptr, csr_src, (float4*)agg);
        // z1 = ReLU(((1+eps)*h + agg) @ W1 + b1)   (in-place into agg)
        mlp_kernel<<<gemmBlocks, blk, 0, stream>>>(
            agg, hin, eps + layer, W1 + (size_t)layer * D * D,
            b1 + (size_t)layer * D, agg, nullptr, nullptr, 1, N_NODES);
        const bool bn = (layer < 3);
        if (bn) hipMemsetAsync(statsSum, 0, 2 * D * sizeof(float), stream);
        // z2 = z1 @ W2 + b2  -> Hbuf  (+ column stats for BN)
        mlp_kernel<<<gemmBlocks, blk, 0, stream>>>(
            agg, nullptr, nullptr, W2 + (size_t)layer * D * D,
            b2 + (size_t)layer * D, Hbuf,
            bn ? statsSum : nullptr, bn ? statsSq : nullptr, 0, N_NODES);
        if (bn) bn_kernel<<<elemBlocks, blk, 0, stream>>>(
            (float4*)Hbuf, statsSum, statsSq,
            (const float4*)(gamma + (size_t)layer * D),
            (const float4*)(beta + (size_t)layer * D), N_NODES);
    }

    hipMemsetAsync(out, 0, (size_t)NUM_GRAPHS * D * sizeof(float), stream);
    pool_kernel<<<elemBlocks, blk, 0, stream>>>(
        (const float4*)Hbuf, batch, out);
}

// Round 3
// 871.944 us; speedup vs baseline: 7.8054x; 2.1211x over previous
//
#include <hip/hip_runtime.h>

#define N_NODES 50000
#define N_EDGES 800000
#define D 128
#define NUM_GRAPHS 128

__device__ __forceinline__ float4 f4zero() { return make_float4(0.f, 0.f, 0.f, 0.f); }

// ===========================================================================
// CSR build
// ===========================================================================
__global__ __launch_bounds__(256) void hist_kernel(
    const int* __restrict__ dst, int* __restrict__ deg)
{
    int e = blockIdx.x * 256 + threadIdx.x;
    if (e < N_EDGES) atomicAdd(&deg[dst[e]], 1);
}

// Per-block inclusive scan (shfl-based), writes partial row_ptr + block sums
__global__ __launch_bounds__(256) void scan_block_kernel(
    const int* __restrict__ deg, int* __restrict__ row_ptr,
    int* __restrict__ blockSum)
{
    __shared__ int wsum[4];
    int t = threadIdx.x, b = blockIdx.x;
    int i = b * 256 + t;
    int v = (i < N_NODES) ? deg[i] : 0;
    int lane = t & 63, wid = t >> 6;
    #pragma unroll
    for (int off = 1; off < 64; off <<= 1) {
        int u = __shfl_up(v, off, 64);
        if (lane >= off) v += u;
    }
    if (lane == 63) wsum[wid] = v;
    __syncthreads();
    int add = 0;
    for (int w = 0; w < wid; ++w) add += wsum[w];
    v += add;
    if (i < N_NODES) row_ptr[i + 1] = v;
    if (t == 255) blockSum[b] = v;
}

// Single-block inclusive scan of block sums (nb <= 256)
__global__ __launch_bounds__(256) void scan_top_kernel(int* blockSum, int nb)
{
    __shared__ int wsum[4];
    int t = threadIdx.x;
    int v = (t < nb) ? blockSum[t] : 0;
    int lane = t & 63, wid = t >> 6;
    #pragma unroll
    for (int off = 1; off < 64; off <<= 1) {
        int u = __shfl_up(v, off, 64);
        if (lane >= off) v += u;
    }
    if (lane == 63) wsum[wid] = v;
    __syncthreads();
    int add = 0;
    for (int w = 0; w < wid; ++w) add += wsum[w];
    v += add;
    if (t < nb) blockSum[t] = v;
}

__global__ __launch_bounds__(256) void scan_add_kernel(
    const int* __restrict__ blockSum, int* __restrict__ row_ptr)
{
    int t = threadIdx.x, b = blockIdx.x;
    int i = b * 256 + t;
    if (b > 0 && i < N_NODES) row_ptr[i + 1] += blockSum[b - 1];
    if (i == 0) row_ptr[0] = 0;
}

__global__ __launch_bounds__(256) void fill_kernel(
    const int* __restrict__ src, const int* __restrict__ dst,
    const int* __restrict__ row_ptr, int* __restrict__ cursor,
    int* __restrict__ csr_src)
{
    int e = blockIdx.x * 256 + threadIdx.x;
    if (e >= N_EDGES) return;
    int d = dst[e];
    int pos = atomicAdd(&cursor[d], 1);
    csr_src[row_ptr[d] + pos] = src[e];
}

// ===========================================================================
// Fused gather:  A[n] = (1+eps)*y(h[n]) + sum_{j in N(n)} y(h[j])
// where y(v) = relu(a*v + b) if BN params given (prev layer's BN), else v.
// 32 lanes per node, float4 per lane.
// ===========================================================================
__global__ __launch_bounds__(256) void gather_kernel(
    const float4* __restrict__ H, const int* __restrict__ row_ptr,
    const int* __restrict__ csr_src, const float* __restrict__ abn,
    const float* __restrict__ bbn, const float* __restrict__ epsp,
    float4* __restrict__ A)
{
    int node = blockIdx.x * 8 + (threadIdx.x >> 5);
    if (node >= N_NODES) return;
    int lane = threadIdx.x & 31;
    const bool bn = (abn != nullptr);
    float4 sa = make_float4(1.f, 1.f, 1.f, 1.f);
    float4 sb = f4zero();
    if (bn) { sa = ((const float4*)abn)[lane]; sb = ((const float4*)bbn)[lane]; }
    float eps1 = 1.0f + *epsp;
    int beg = row_ptr[node], end = row_ptr[node + 1];

    float4 v = H[node * 32 + lane];
    if (bn) {
        v.x = fmaxf(sa.x * v.x + sb.x, 0.f);
        v.y = fmaxf(sa.y * v.y + sb.y, 0.f);
        v.z = fmaxf(sa.z * v.z + sb.z, 0.f);
        v.w = fmaxf(sa.w * v.w + sb.w, 0.f);
    }
    float4 acc = make_float4(eps1 * v.x, eps1 * v.y, eps1 * v.z, eps1 * v.w);

    for (int base = beg; base < end; base += 32) {
        int idx = 0;
        if (base + lane < end) idx = csr_src[base + lane];
        int cnt = min(32, end - base);
        for (int j = 0; j < cnt; ++j) {
            int s = __shfl(idx, j, 32);
            float4 u = H[s * 32 + lane];
            if (bn) {
                u.x = fmaxf(sa.x * u.x + sb.x, 0.f);
                u.y = fmaxf(sa.y * u.y + sb.y, 0.f);
                u.z = fmaxf(sa.z * u.z + sb.z, 0.f);
                u.w = fmaxf(sa.w * u.w + sb.w, 0.f);
            }
            acc.x += u.x; acc.y += u.y; acc.z += u.z; acc.w += u.w;
        }
    }
    A[node * 32 + lane] = acc;
}

// ===========================================================================
// out = [ReLU]( A @ W + bias ),  optional per-column sum/sumsq (BN stats).
// Block: 256 thr, tile 128 rows x 128 cols, K chunked by 32.
// Thread: 8 rows x 8 cols (2 float4 col-groups). LDS 33KB -> 3-4 blocks/CU.
// out may alias A (block reads only its own rows; writes after all reads).
// ===========================================================================
__global__ __launch_bounds__(256, 3) void mlp_kernel(
    const float* __restrict__ A,
    const float* __restrict__ W,
    const float* __restrict__ bias,
    float* __restrict__ out,
    float* __restrict__ statsSum,
    float* __restrict__ statsSq,
    int relu, int M)
{
    __shared__ float Alds[128 * 32];
    __shared__ float Wlds[32 * 128];
    __shared__ float ssum[128];
    __shared__ float ssq[128];

    const int tid = threadIdx.x;
    const int tx  = tid & 15;    // col4 pair: cols4 {tx, tx+16}
    const int ty  = tid >> 4;    // rows ty*8 .. ty*8+7
    const int row0 = blockIdx.x * 128;
    const bool doStats = (statsSum != nullptr);
    if (doStats && tid < 128) { ssum[tid] = 0.f; ssq[tid] = 0.f; }

    const float4* A4 = (const float4*)A;
    const float4* W4 = (const float4*)W;
    float4* Alds4 = (float4*)Alds;
    float4* Wlds4 = (float4*)Wlds;

    float4 acc[8][2];
    #pragma unroll
    for (int r = 0; r < 8; ++r) { acc[r][0] = f4zero(); acc[r][1] = f4zero(); }

    for (int kc = 0; kc < 4; ++kc) {
        __syncthreads();
        #pragma unroll
        for (int i = 0; i < 4; ++i) {           // A chunk: 128 rows x 8 f4
            int fi = i * 256 + tid;
            int r = fi >> 3, c = fi & 7;
            int gr = row0 + r;
            Alds4[fi] = (gr < M) ? A4[gr * 32 + kc * 8 + c] : f4zero();
        }
        #pragma unroll
        for (int i = 0; i < 4; ++i) {           // W chunk: 32 k x 32 f4
            int fi = i * 256 + tid;
            Wlds4[fi] = W4[kc * 1024 + fi];
        }
        __syncthreads();

        for (int kq = 0; kq < 8; ++kq) {
            float4 w0[4], w1[4];
            #pragma unroll
            for (int kk = 0; kk < 4; ++kk) {
                w0[kk] = Wlds4[(kq * 4 + kk) * 32 + tx];
                w1[kk] = Wlds4[(kq * 4 + kk) * 32 + tx + 16];
            }
            #pragma unroll
            for (int rr = 0; rr < 8; ++rr) {
                float4 a = Alds4[(ty * 8 + rr) * 8 + kq];
                acc[rr][0].x += a.x*w0[0].x + a.y*w0[1].x + a.z*w0[2].x + a.w*w0[3].x;
                acc[rr][0].y += a.x*w0[0].y + a.y*w0[1].y + a.z*w0[2].y + a.w*w0[3].y;
                acc[rr][0].z += a.x*w0[0].z + a.y*w0[1].z + a.z*w0[2].z + a.w*w0[3].z;
                acc[rr][0].w += a.x*w0[0].w + a.y*w0[1].w + a.z*w0[2].w + a.w*w0[3].w;
                acc[rr][1].x += a.x*w1[0].x + a.y*w1[1].x + a.z*w1[2].x + a.w*w1[3].x;
                acc[rr][1].y += a.x*w1[0].y + a.y*w1[1].y + a.z*w1[2].y + a.w*w1[3].y;
                acc[rr][1].z += a.x*w1[0].z + a.y*w1[1].z + a.z*w1[2].z + a.w*w1[3].z;
                acc[rr][1].w += a.x*w1[0].w + a.y*w1[1].w + a.z*w1[2].w + a.w*w1[3].w;
            }
        }
    }

    // ---- epilogue ----
    const float4 b0 = ((const float4*)bias)[tx];
    const float4 b1 = ((const float4*)bias)[tx + 16];
    float4 locS[2] = {f4zero(), f4zero()};
    float4 locQ[2] = {f4zero(), f4zero()};
    float4* out4 = (float4*)out;
    #pragma unroll
    for (int rr = 0; rr < 8; ++rr) {
        int gr = row0 + ty * 8 + rr;
        if (gr >= M) continue;
        float4 v0, v1;
        v0.x = acc[rr][0].x + b0.x; v0.y = acc[rr][0].y + b0.y;
        v0.z = acc[rr][0].z + b0.z; v0.w = acc[rr][0].w + b0.w;
        v1.x = acc[rr][1].x + b1.x; v1.y = acc[rr][1].y + b1.y;
        v1.z = acc[rr][1].z + b1.z; v1.w = acc[rr][1].w + b1.w;
        if (relu) {
            v0.x = fmaxf(v0.x, 0.f); v0.y = fmaxf(v0.y, 0.f);
            v0.z = fmaxf(v0.z, 0.f); v0.w = fmaxf(v0.w, 0.f);
            v1.x = fmaxf(v1.x, 0.f); v1.y = fmaxf(v1.y, 0.f);
            v1.z = fmaxf(v1.z, 0.f); v1.w = fmaxf(v1.w, 0.f);
        }
        out4[gr * 32 + tx]      = v0;
        out4[gr * 32 + tx + 16] = v1;
        if (doStats) {
            locS[0].x += v0.x; locS[0].y += v0.y; locS[0].z += v0.z; locS[0].w += v0.w;
            locS[1].x += v1.x; locS[1].y += v1.y; locS[1].z += v1.z; locS[1].w += v1.w;
            locQ[0].x += v0.x*v0.x; locQ[0].y += v0.y*v0.y;
            locQ[0].z += v0.z*v0.z; locQ[0].w += v0.w*v0.w;
            locQ[1].x += v1.x*v1.x; locQ[1].y += v1.y*v1.y;
            locQ[1].z += v1.z*v1.z; locQ[1].w += v1.w*v1.w;
        }
    }
    if (doStats) {
        atomicAdd(&ssum[4*tx+0],      locS[0].x); atomicAdd(&ssum[4*tx+1],      locS[0].y);
        atomicAdd(&ssum[4*tx+2],      locS[0].z); atomicAdd(&ssum[4*tx+3],      locS[0].w);
        atomicAdd(&ssum[4*(tx+16)+0], locS[1].x); atomicAdd(&ssum[4*(tx+16)+1], locS[1].y);
        atomicAdd(&ssum[4*(tx+16)+2], locS[1].z); atomicAdd(&ssum[4*(tx+16)+3], locS[1].w);
        atomicAdd(&ssq[4*tx+0],      locQ[0].x); atomicAdd(&ssq[4*tx+1],      locQ[0].y);
        atomicAdd(&ssq[4*tx+2],      locQ[0].z); atomicAdd(&ssq[4*tx+3],      locQ[0].w);
        atomicAdd(&ssq[4*(tx+16)+0], locQ[1].x); atomicAdd(&ssq[4*(tx+16)+1], locQ[1].y);
        atomicAdd(&ssq[4*(tx+16)+2], locQ[1].z); atomicAdd(&ssq[4*(tx+16)+3], locQ[1].w);
        __syncthreads();
        if (tid < 128) {
            atomicAdd(&statsSum[tid], ssum[tid]);
            atomicAdd(&statsSq[tid],  ssq[tid]);
        }
    }
}

// ===========================================================================
// BN stats -> per-column scale/bias:  a = gamma*rsqrt(var+eps), b = beta - mu*a
// ===========================================================================
__global__ void bnscale_kernel(
    const float* __restrict__ sum, const float* __restrict__ sq,
    const float* __restrict__ gamma, const float* __restrict__ beta,
    float* __restrict__ a, float* __restrict__ b)
{
    int c = threadIdx.x;
    float invN = 1.0f / (float)N_NODES;
    float mu = sum[c] * invN;
    float var = sq[c] * invN - mu * mu;
    float ai = gamma[c] * rsqrtf(var + 1e-5f);
    a[c] = ai;
    b[c] = beta[c] - mu * ai;
}

// ===========================================================================
// global_add_pool: batch is SORTED -> one wave per graph, no atomics.
// ===========================================================================
__global__ __launch_bounds__(256) void pool_kernel(
    const float2* __restrict__ H, const int* __restrict__ batch,
    float2* __restrict__ out)
{
    int g = blockIdx.x * 4 + (threadIdx.x >> 6);
    int lane = threadIdx.x & 63;
    if (g >= NUM_GRAPHS) return;
    int lo = 0, hi = N_NODES;
    while (lo < hi) { int mid = (lo + hi) >> 1; if (batch[mid] < g) lo = mid + 1; else hi = mid; }
    int s0 = lo;
    lo = s0; hi = N_NODES;
    while (lo < hi) { int mid = (lo + hi) >> 1; if (batch[mid] < g + 1) lo = mid + 1; else hi = mid; }
    int s1 = lo;
    float2 acc = make_float2(0.f, 0.f);
    for (int i = s0; i < s1; ++i) {
        float2 v = H[i * 64 + lane];
        acc.x += v.x; acc.y += v.y;
    }
    out[g * 64 + lane] = acc;
}

extern "C" void kernel_launch(void* const* d_in, const int* in_sizes, int n_in,
                              void* d_out, int out_size, void* d_ws, size_t ws_size,
                              hipStream_t stream)
{
    const float* x     = (const float*)d_in[0];
    const int*   ei    = (const int*)d_in[1];
    const int*   batch = (const int*)d_in[2];
    const float* W1    = (const float*)d_in[3];
    const float* b1    = (const float*)d_in[4];
    const float* W2    = (const float*)d_in[5];
    const float* b2    = (const float*)d_in[6];
    const float* eps   = (const float*)d_in[7];
    const float* gamma = (const float*)d_in[8];
    const float* beta  = (const float*)d_in[9];
    float* out = (float*)d_out;

    // ---- workspace layout ----
    float* agg      = (float*)d_ws;                  // [N,D]; z1 in-place
    float* Hbuf     = agg + (size_t)N_NODES * D;     // [N,D] raw z2 (pre-BN)
    float* statsSum = Hbuf + (size_t)N_NODES * D;    // [D]
    float* statsSq  = statsSum + D;                  // [D]
    float* abn      = statsSq + D;                   // [D]
    float* bbn      = abn + D;                       // [D]
    int*   deg      = (int*)(bbn + D);               // [N]
    int*   cursor   = deg + N_NODES;                 // [N]
    int*   row_ptr  = cursor + N_NODES;              // [N+1]
    int*   blockSum = row_ptr + N_NODES + 1;         // [256]
    int*   csr_src  = blockSum + 256;                // [E]

    const int* src = ei;
    const int* dst = ei + N_EDGES;

    dim3 blk(256);
    const int gemmBlocks   = (N_NODES + 127) / 128;      // 391
    const int edgeBlocks   = (N_EDGES + 255) / 256;      // 3125
    const int gatherBlocks = (N_NODES + 7) / 8;          // 6250
    const int scanBlocks   = (N_NODES + 255) / 256;      // 196

    // ---- build CSR ----
    hipMemsetAsync(deg, 0, (size_t)(2 * N_NODES) * sizeof(int), stream); // deg+cursor
    hist_kernel<<<edgeBlocks, blk, 0, stream>>>(dst, deg);
    scan_block_kernel<<<scanBlocks, blk, 0, stream>>>(deg, row_ptr, blockSum);
    scan_top_kernel<<<1, blk, 0, stream>>>(blockSum, scanBlocks);
    scan_add_kernel<<<scanBlocks, blk, 0, stream>>>(blockSum, row_ptr);
    fill_kernel<<<edgeBlocks, blk, 0, stream>>>(src, dst, row_ptr, cursor, csr_src);

    for (int layer = 0; layer < 4; ++layer) {
        const float* hin = (layer == 0) ? x : Hbuf;
        const float* a = (layer == 0) ? nullptr : abn;
        const float* b = (layer == 0) ? nullptr : bbn;
        // A = (1+eps)*y(h) + sum y(h_nb)   (y = BN+ReLU of prev layer, fused)
        gather_kernel<<<gatherBlocks, blk, 0, stream>>>(
            (const float4*)hin, row_ptr, csr_src, a, b, eps + layer, (float4*)agg);
        // z1 = ReLU(A @ W1 + b1)  (in-place)
        mlp_kernel<<<gemmBlocks, blk, 0, stream>>>(
            agg, W1 + (size_t)layer * D * D, b1 + (size_t)layer * D,
            agg, nullptr, nullptr, 1, N_NODES);
        const bool bn = (layer < 3);
        if (bn) hipMemsetAsync(statsSum, 0, 2 * D * sizeof(float), stream);
        // z2 = z1 @ W2 + b2 -> Hbuf (+ BN stats)
        mlp_kernel<<<gemmBlocks, blk, 0, stream>>>(
            agg, W2 + (size_t)layer * D * D, b2 + (size_t)layer * D,
            Hbuf, bn ? statsSum : nullptr, bn ? statsSq : nullptr, 0, N_NODES);
        if (bn) bnscale_kernel<<<1, 128, 0, stream>>>(
            statsSum, statsSq, gamma + (size_t)layer * D, beta + (size_t)layer * D,
            abn, bbn);
    }

    pool_kernel<<<32, blk, 0, stream>>>(
        (const float2*)Hbuf, batch, (float2*)out);
}

// Round 4
// 681.953 us; speedup vs baseline: 9.9800x; 1.2786x over previous
//
#include <hip/hip_runtime.h>

#define N_NODES 50000
#define N_EDGES 800000
#define D 128
#define NUM_GRAPHS 128

typedef __attribute__((ext_vector_type(8))) short bfrag8;
typedef __attribute__((ext_vector_type(4))) float f32x4;

__device__ __forceinline__ float4 f4zero() { return make_float4(0.f, 0.f, 0.f, 0.f); }

// fp32 -> bf16 bits, round-to-nearest-even
__device__ __forceinline__ short f2bf(float f) {
    unsigned u = __float_as_uint(f);
    unsigned r = (u + 0x7fffu + ((u >> 16) & 1u)) >> 16;
    return (short)r;
}

// ===========================================================================
// CSR build
// ===========================================================================
__global__ __launch_bounds__(256) void hist_kernel(
    const int* __restrict__ dst, int* __restrict__ deg)
{
    int e = blockIdx.x * 256 + threadIdx.x;
    if (e < N_EDGES) atomicAdd(&deg[dst[e]], 1);
}

__global__ __launch_bounds__(256) void scan_block_kernel(
    const int* __restrict__ deg, int* __restrict__ row_ptr,
    int* __restrict__ blockSum)
{
    __shared__ int wsum[4];
    int t = threadIdx.x, b = blockIdx.x;
    int i = b * 256 + t;
    int v = (i < N_NODES) ? deg[i] : 0;
    int lane = t & 63, wid = t >> 6;
    #pragma unroll
    for (int off = 1; off < 64; off <<= 1) {
        int u = __shfl_up(v, off, 64);
        if (lane >= off) v += u;
    }
    if (lane == 63) wsum[wid] = v;
    __syncthreads();
    int add = 0;
    for (int w = 0; w < wid; ++w) add += wsum[w];
    v += add;
    if (i < N_NODES) row_ptr[i + 1] = v;
    if (t == 255) blockSum[b] = v;
}

__global__ __launch_bounds__(256) void scan_top_kernel(int* blockSum, int nb)
{
    __shared__ int wsum[4];
    int t = threadIdx.x;
    int v = (t < nb) ? blockSum[t] : 0;
    int lane = t & 63, wid = t >> 6;
    #pragma unroll
    for (int off = 1; off < 64; off <<= 1) {
        int u = __shfl_up(v, off, 64);
        if (lane >= off) v += u;
    }
    if (lane == 63) wsum[wid] = v;
    __syncthreads();
    int add = 0;
    for (int w = 0; w < wid; ++w) add += wsum[w];
    v += add;
    if (t < nb) blockSum[t] = v;
}

__global__ __launch_bounds__(256) void scan_add_kernel(
    const int* __restrict__ blockSum, int* __restrict__ row_ptr)
{
    int t = threadIdx.x, b = blockIdx.x;
    int i = b * 256 + t;
    if (b > 0 && i < N_NODES) row_ptr[i + 1] += blockSum[b - 1];
    if (i == 0) row_ptr[0] = 0;
}

__global__ __launch_bounds__(256) void fill_kernel(
    const int* __restrict__ src, const int* __restrict__ dst,
    const int* __restrict__ row_ptr, int* __restrict__ cursor,
    int* __restrict__ csr_src)
{
    int e = blockIdx.x * 256 + threadIdx.x;
    if (e >= N_EDGES) return;
    int d = dst[e];
    int pos = atomicAdd(&cursor[d], 1);
    csr_src[row_ptr[d] + pos] = src[e];
}

// ===========================================================================
// W[k][n] fp32 -> Wt[n][k] bf16 bits, 8 matrices (W1[0..3], W2[0..3])
// ===========================================================================
__global__ __launch_bounds__(256) void wconv_kernel(
    const float* __restrict__ W1, const float* __restrict__ W2,
    short* __restrict__ Wt)
{
    int idx = blockIdx.x * 256 + threadIdx.x;     // 0 .. 8*16384-1
    int m = idx >> 14;
    int rem = idx & 16383;
    int k = rem >> 7;
    int n = rem & 127;
    const float* W = (m < 4) ? (W1 + (size_t)m * 16384)
                             : (W2 + (size_t)(m - 4) * 16384);
    Wt[(size_t)m * 16384 + n * 128 + k] = f2bf(W[k * 128 + n]);
}

// ===========================================================================
// Fused gather:  A[n] = (1+eps)*y(h[n]) + sum_{j in N(n)} y(h[j])
// y(v) = relu(a*v + b) if BN params given (prev layer's BN), else v.
// ===========================================================================
__global__ __launch_bounds__(256) void gather_kernel(
    const float4* __restrict__ H, const int* __restrict__ row_ptr,
    const int* __restrict__ csr_src, const float* __restrict__ abn,
    const float* __restrict__ bbn, const float* __restrict__ epsp,
    float4* __restrict__ A)
{
    int node = blockIdx.x * 8 + (threadIdx.x >> 5);
    if (node >= N_NODES) return;
    int lane = threadIdx.x & 31;
    const bool bn = (abn != nullptr);
    float4 sa = make_float4(1.f, 1.f, 1.f, 1.f);
    float4 sb = f4zero();
    if (bn) { sa = ((const float4*)abn)[lane]; sb = ((const float4*)bbn)[lane]; }
    float eps1 = 1.0f + *epsp;
    int beg = row_ptr[node], end = row_ptr[node + 1];

    float4 v = H[node * 32 + lane];
    if (bn) {
        v.x = fmaxf(sa.x * v.x + sb.x, 0.f);
        v.y = fmaxf(sa.y * v.y + sb.y, 0.f);
        v.z = fmaxf(sa.z * v.z + sb.z, 0.f);
        v.w = fmaxf(sa.w * v.w + sb.w, 0.f);
    }
    float4 acc = make_float4(eps1 * v.x, eps1 * v.y, eps1 * v.z, eps1 * v.w);

    for (int base = beg; base < end; base += 32) {
        int idx = 0;
        if (base + lane < end) idx = csr_src[base + lane];
        int cnt = min(32, end - base);
        for (int j = 0; j < cnt; ++j) {
            int s = __shfl(idx, j, 32);
            float4 u = H[s * 32 + lane];
            if (bn) {
                u.x = fmaxf(sa.x * u.x + sb.x, 0.f);
                u.y = fmaxf(sa.y * u.y + sb.y, 0.f);
                u.z = fmaxf(sa.z * u.z + sb.z, 0.f);
                u.w = fmaxf(sa.w * u.w + sb.w, 0.f);
            }
            acc.x += u.x; acc.y += u.y; acc.z += u.z; acc.w += u.w;
        }
    }
    A[node * 32 + lane] = acc;
}

// ===========================================================================
// out = [ReLU]( A @ W + bias )  via bf16 MFMA 16x16x32, fp32 accumulate.
// A fp32 [M,128]; Wt bf16-bits [128(n),128(k)]; out fp32 [M,128].
// Block 256 = 4 waves; wave computes 16 rows x 128 cols. No LDS in K-loop.
// A-frag: lane(m=lane&15, q=lane>>4) holds A[m][kk*32+q*8 .. +7].
// B-frag: lane holds Wt[n=lane&15 (+16*ct)][kk*32+q*8 .. +7].
// C/D: col = ct*16 + (lane&15), row = q*4 + reg.
// out may alias A (wave reads only its own rows, before its stores).
// M must be a multiple of 16 (50000 ✓).
// ===========================================================================
__global__ __launch_bounds__(256) void mlp_kernel(
    const float* __restrict__ A,
    const short* __restrict__ Wt,
    const float* __restrict__ bias,
    float* __restrict__ out,
    float* __restrict__ statsSum,
    float* __restrict__ statsSq,
    int relu, int M)
{
    __shared__ float ssum[128];
    __shared__ float ssq[128];
    const int tid  = threadIdx.x;
    const int wv   = tid >> 6;
    const int lane = tid & 63;
    const int q    = lane >> 4;
    const int mrow = lane & 15;
    const int row0 = blockIdx.x * 64 + wv * 16;
    const bool doStats = (statsSum != nullptr);
    if (doStats) {
        if (tid < 128) { ssum[tid] = 0.f; ssq[tid] = 0.f; }
        __syncthreads();
    }
    const bool active = (row0 < M);

    f32x4 acc[8];
    #pragma unroll
    for (int ct = 0; ct < 8; ++ct) acc[ct] = (f32x4){0.f, 0.f, 0.f, 0.f};

    if (active) {
        // preload + convert the 4 A fragments (this wave's row, all K-steps)
        bfrag8 af[4];
        const float* ap = A + (size_t)(row0 + mrow) * 128 + q * 8;
        #pragma unroll
        for (int kk = 0; kk < 4; ++kk) {
            float4 lo = *(const float4*)(ap + kk * 32);
            float4 hi = *(const float4*)(ap + kk * 32 + 4);
            bfrag8 a;
            a[0] = f2bf(lo.x); a[1] = f2bf(lo.y); a[2] = f2bf(lo.z); a[3] = f2bf(lo.w);
            a[4] = f2bf(hi.x); a[5] = f2bf(hi.y); a[6] = f2bf(hi.z); a[7] = f2bf(hi.w);
            af[kk] = a;
        }
        const bfrag8* Wt8 = (const bfrag8*)Wt;   // row stride = 16 bfrag8
        #pragma unroll
        for (int kk = 0; kk < 4; ++kk) {
            #pragma unroll
            for (int ct = 0; ct < 8; ++ct) {
                bfrag8 bf = Wt8[(ct * 16 + mrow) * 16 + kk * 4 + q];
                acc[ct] = __builtin_amdgcn_mfma_f32_16x16x32_bf16(
                    af[kk], bf, acc[ct], 0, 0, 0);
            }
        }
    }

    // ---- epilogue: bias, relu, store fp32, BN stats ----
    #pragma unroll
    for (int ct = 0; ct < 8; ++ct) {
        int col = ct * 16 + mrow;
        float bval = bias[col];
        float s = 0.f, sq = 0.f;
        if (active) {
            #pragma unroll
            for (int r = 0; r < 4; ++r) {
                float v = acc[ct][r] + bval;
                if (relu) v = fmaxf(v, 0.f);
                out[(size_t)(row0 + q * 4 + r) * 128 + col] = v;
                s += v; sq += v * v;
            }
        }
        if (doStats) {
            s  += __shfl_xor(s, 16);  s  += __shfl_xor(s, 32);
            sq += __shfl_xor(sq, 16); sq += __shfl_xor(sq, 32);
            if (q == 0) {
                atomicAdd(&ssum[col], s);
                atomicAdd(&ssq[col], sq);
            }
        }
    }
    if (doStats) {
        __syncthreads();
        if (tid < 128) {
            atomicAdd(&statsSum[tid], ssum[tid]);
            atomicAdd(&statsSq[tid],  ssq[tid]);
        }
    }
}

// ===========================================================================
// BN stats -> per-column scale/bias
// ===========================================================================
__global__ void bnscale_kernel(
    const float* __restrict__ sum, const float* __restrict__ sq,
    const float* __restrict__ gamma, const float* __restrict__ beta,
    float* __restrict__ a, float* __restrict__ b)
{
    int c = threadIdx.x;
    float invN = 1.0f / (float)N_NODES;
    float mu = sum[c] * invN;
    float var = sq[c] * invN - mu * mu;
    float ai = gamma[c] * rsqrtf(var + 1e-5f);
    a[c] = ai;
    b[c] = beta[c] - mu * ai;
}

// ===========================================================================
// global_add_pool: batch sorted -> run-length accumulate, flush per run.
// Block handles 256 nodes; thread t: col4 = t&31, node-lane = t>>5 (stride 8).
// ===========================================================================
__global__ __launch_bounds__(256) void pool_kernel(
    const float4* __restrict__ H, const int* __restrict__ batch,
    float* __restrict__ out)
{
    int c4 = threadIdx.x & 31;
    int nl = threadIdx.x >> 5;
    int node0 = blockIdx.x * 256;
    float4 acc = f4zero();
    int gcur = -1;
    for (int i = nl; i < 256; i += 8) {
        int n = node0 + i;
        if (n >= N_NODES) break;
        int g = batch[n];
        if (g != gcur) {
            if (gcur >= 0) {
                float* o = out + gcur * D + c4 * 4;
                atomicAdd(o + 0, acc.x); atomicAdd(o + 1, acc.y);
                atomicAdd(o + 2, acc.z); atomicAdd(o + 3, acc.w);
            }
            gcur = g;
            acc = f4zero();
        }
        float4 v = H[n * 32 + c4];
        acc.x += v.x; acc.y += v.y; acc.z += v.z; acc.w += v.w;
    }
    if (gcur >= 0) {
        float* o = out + gcur * D + c4 * 4;
        atomicAdd(o + 0, acc.x); atomicAdd(o + 1, acc.y);
        atomicAdd(o + 2, acc.z); atomicAdd(o + 3, acc.w);
    }
}

extern "C" void kernel_launch(void* const* d_in, const int* in_sizes, int n_in,
                              void* d_out, int out_size, void* d_ws, size_t ws_size,
                              hipStream_t stream)
{
    const float* x     = (const float*)d_in[0];
    const int*   ei    = (const int*)d_in[1];
    const int*   batch = (const int*)d_in[2];
    const float* W1    = (const float*)d_in[3];
    const float* b1    = (const float*)d_in[4];
    const float* W2    = (const float*)d_in[5];
    const float* b2    = (const float*)d_in[6];
    const float* eps   = (const float*)d_in[7];
    const float* gamma = (const float*)d_in[8];
    const float* beta  = (const float*)d_in[9];
    float* out = (float*)d_out;

    // ---- workspace layout ----
    float* agg      = (float*)d_ws;                  // [N,D]; z1 in-place
    float* Hbuf     = agg + (size_t)N_NODES * D;     // [N,D]
    float* statsSum = Hbuf + (size_t)N_NODES * D;    // [D]
    float* statsSq  = statsSum + D;                  // [D]
    float* abn      = statsSq + D;                   // [D]
    float* bbn      = abn + D;                       // [D]
    int*   deg      = (int*)(bbn + D);               // [N]
    int*   cursor   = deg + N_NODES;                 // [N]
    int*   row_ptr  = cursor + N_NODES;              // [N+1]
    int*   blockSum = row_ptr + N_NODES + 1;         // [256]
    int*   csr_src  = blockSum + 256;                // [E]
    short* Wt       = (short*)(csr_src + N_EDGES);   // [8][128][128] bf16 bits

    const int* src = ei;
    const int* dst = ei + N_EDGES;

    dim3 blk(256);
    const int gemmBlocks   = (N_NODES + 63) / 64;        // 782
    const int edgeBlocks   = (N_EDGES + 255) / 256;      // 3125
    const int gatherBlocks = (N_NODES + 7) / 8;          // 6250
    const int scanBlocks   = (N_NODES + 255) / 256;      // 196
    const int poolBlocks   = (N_NODES + 255) / 256;      // 196

    // ---- one-time prep: CSR + W conversion ----
    hipMemsetAsync(deg, 0, (size_t)(2 * N_NODES) * sizeof(int), stream);
    hist_kernel<<<edgeBlocks, blk, 0, stream>>>(dst, deg);
    wconv_kernel<<<512, blk, 0, stream>>>(W1, W2, Wt);
    scan_block_kernel<<<scanBlocks, blk, 0, stream>>>(deg, row_ptr, blockSum);
    scan_top_kernel<<<1, blk, 0, stream>>>(blockSum, scanBlocks);
    scan_add_kernel<<<scanBlocks, blk, 0, stream>>>(blockSum, row_ptr);
    fill_kernel<<<edgeBlocks, blk, 0, stream>>>(src, dst, row_ptr, cursor, csr_src);

    for (int layer = 0; layer < 4; ++layer) {
        const float* hin = (layer == 0) ? x : Hbuf;
        const float* a = (layer == 0) ? nullptr : abn;
        const float* b = (layer == 0) ? nullptr : bbn;
        gather_kernel<<<gatherBlocks, blk, 0, stream>>>(
            (const float4*)hin, row_ptr, csr_src, a, b, eps + layer, (float4*)agg);
        // z1 = ReLU(A @ W1 + b1)  (in-place into agg)
        mlp_kernel<<<gemmBlocks, blk, 0, stream>>>(
            agg, Wt + (size_t)layer * 16384, b1 + (size_t)layer * D,
            agg, nullptr, nullptr, 1, N_NODES);
        const bool bn = (layer < 3);
        if (bn) hipMemsetAsync(statsSum, 0, 2 * D * sizeof(float), stream);
        // z2 = z1 @ W2 + b2 -> Hbuf (+ BN stats)
        mlp_kernel<<<gemmBlocks, blk, 0, stream>>>(
            agg, Wt + (size_t)(4 + layer) * 16384, b2 + (size_t)layer * D,
            Hbuf, bn ? statsSum : nullptr, bn ? statsSq : nullptr, 0, N_NODES);
        if (bn) bnscale_kernel<<<1, 128, 0, stream>>>(
            statsSum, statsSq, gamma + (size_t)layer * D, beta + (size_t)layer * D,
            abn, bbn);
    }

    hipMemsetAsync(out, 0, (size_t)NUM_GRAPHS * D * sizeof(float), stream);
    pool_kernel<<<poolBlocks, blk, 0, stream>>>(
        (const float4*)Hbuf, batch, out);
}

// Round 5
// 560.089 us; speedup vs baseline: 12.1514x; 1.2176x over previous
//
#include <hip/hip_runtime.h>

#define N_NODES 50000
#define N_EDGES 800000
#define D 128
#define NUM_GRAPHS 128
#define LSTR 136   // LDS row stride in shorts (272B: 16B-aligned, spreads banks)

typedef __attribute__((ext_vector_type(8))) short bfrag8;
typedef __attribute__((ext_vector_type(4))) float f32x4;

__device__ __forceinline__ float4 f4zero() { return make_float4(0.f, 0.f, 0.f, 0.f); }

// fp32 -> bf16 bits, round-to-nearest-even
__device__ __forceinline__ unsigned short f2bf(float f) {
    unsigned u = __float_as_uint(f);
    unsigned r = (u + 0x7fffu + ((u >> 16) & 1u)) >> 16;
    return (unsigned short)r;
}
__device__ __forceinline__ float bf2f(unsigned short b) {
    return __uint_as_float(((unsigned)b) << 16);
}
__device__ __forceinline__ float4 bf2f4(ushort4 u) {
    return make_float4(bf2f(u.x), bf2f(u.y), bf2f(u.z), bf2f(u.w));
}

// ===========================================================================
// CSR build
// ===========================================================================
__global__ __launch_bounds__(256) void hist_kernel(
    const int* __restrict__ dst, int* __restrict__ deg)
{
    int e = blockIdx.x * 256 + threadIdx.x;
    if (e < N_EDGES) atomicAdd(&deg[dst[e]], 1);
}

__global__ __launch_bounds__(256) void scan_block_kernel(
    const int* __restrict__ deg, int* __restrict__ row_ptr,
    int* __restrict__ blockSum)
{
    __shared__ int wsum[4];
    int t = threadIdx.x, b = blockIdx.x;
    int i = b * 256 + t;
    int v = (i < N_NODES) ? deg[i] : 0;
    int lane = t & 63, wid = t >> 6;
    #pragma unroll
    for (int off = 1; off < 64; off <<= 1) {
        int u = __shfl_up(v, off, 64);
        if (lane >= off) v += u;
    }
    if (lane == 63) wsum[wid] = v;
    __syncthreads();
    int add = 0;
    for (int w = 0; w < wid; ++w) add += wsum[w];
    v += add;
    if (i < N_NODES) row_ptr[i + 1] = v;
    if (t == 255) blockSum[b] = v;
}

__global__ __launch_bounds__(256) void scan_top_kernel(int* blockSum, int nb)
{
    __shared__ int wsum[4];
    int t = threadIdx.x;
    int v = (t < nb) ? blockSum[t] : 0;
    int lane = t & 63, wid = t >> 6;
    #pragma unroll
    for (int off = 1; off < 64; off <<= 1) {
        int u = __shfl_up(v, off, 64);
        if (lane >= off) v += u;
    }
    if (lane == 63) wsum[wid] = v;
    __syncthreads();
    int add = 0;
    for (int w = 0; w < wid; ++w) add += wsum[w];
    v += add;
    if (t < nb) blockSum[t] = v;
}

__global__ __launch_bounds__(256) void scan_add_kernel(
    const int* __restrict__ blockSum, int* __restrict__ row_ptr)
{
    int t = threadIdx.x, b = blockIdx.x;
    int i = b * 256 + t;
    if (b > 0 && i < N_NODES) row_ptr[i + 1] += blockSum[b - 1];
    if (i == 0) row_ptr[0] = 0;
}

__global__ __launch_bounds__(256) void fill_kernel(
    const int* __restrict__ src, const int* __restrict__ dst,
    const int* __restrict__ row_ptr, int* __restrict__ cursor,
    int* __restrict__ csr_src)
{
    int e = blockIdx.x * 256 + threadIdx.x;
    if (e >= N_EDGES) return;
    int d = dst[e];
    int pos = atomicAdd(&cursor[d], 1);
    csr_src[row_ptr[d] + pos] = src[e];
}

// ===========================================================================
// W[k][n] fp32 -> Wt[n][k] bf16 bits, 8 matrices (W1[0..3], W2[0..3])
// ===========================================================================
__global__ __launch_bounds__(256) void wconv_kernel(
    const float* __restrict__ W1, const float* __restrict__ W2,
    short* __restrict__ Wt)
{
    int idx = blockIdx.x * 256 + threadIdx.x;     // 0 .. 8*16384-1
    int m = idx >> 14;
    int rem = idx & 16383;
    int k = rem >> 7;
    int n = rem & 127;
    const float* W = (m < 4) ? (W1 + (size_t)m * 16384)
                             : (W2 + (size_t)(m - 4) * 16384);
    Wt[(size_t)m * 16384 + n * 128 + k] = (short)f2bf(W[k * 128 + n]);
}

// x fp32 -> bf16 bits
__global__ __launch_bounds__(256) void xconv_kernel(
    const float4* __restrict__ x4, ushort4* __restrict__ o)
{
    int i = blockIdx.x * 256 + threadIdx.x;      // N*32 float4s
    if (i >= N_NODES * 32) return;
    float4 v = x4[i];
    o[i] = make_ushort4(f2bf(v.x), f2bf(v.y), f2bf(v.z), f2bf(v.w));
}

// ===========================================================================
// Fused gather (bf16 in/out):
//   A[n] = bf16( (1+eps)*y(h[n]) + sum_{j in N(n)} y(h[j]) )
// y(v) = relu(a*v + b) if BN params given (prev layer's BN), else v.
// 32 lanes per node, ushort4 (4 cols) per lane; fp32 accumulation.
// ===========================================================================
__global__ __launch_bounds__(256) void gather_kernel(
    const ushort4* __restrict__ H, const int* __restrict__ row_ptr,
    const int* __restrict__ csr_src, const float* __restrict__ abn,
    const float* __restrict__ bbn, const float* __restrict__ epsp,
    ushort4* __restrict__ A)
{
    int node = blockIdx.x * 8 + (threadIdx.x >> 5);
    if (node >= N_NODES) return;
    int lane = threadIdx.x & 31;
    const bool bn = (abn != nullptr);
    float4 sa = make_float4(1.f, 1.f, 1.f, 1.f);
    float4 sb = f4zero();
    if (bn) { sa = ((const float4*)abn)[lane]; sb = ((const float4*)bbn)[lane]; }
    float eps1 = 1.0f + *epsp;
    int beg = row_ptr[node], end = row_ptr[node + 1];

    float4 v = bf2f4(H[node * 32 + lane]);
    if (bn) {
        v.x = fmaxf(sa.x * v.x + sb.x, 0.f);
        v.y = fmaxf(sa.y * v.y + sb.y, 0.f);
        v.z = fmaxf(sa.z * v.z + sb.z, 0.f);
        v.w = fmaxf(sa.w * v.w + sb.w, 0.f);
    }
    float4 acc = make_float4(eps1 * v.x, eps1 * v.y, eps1 * v.z, eps1 * v.w);

    for (int base = beg; base < end; base += 32) {
        int idx = 0;
        if (base + lane < end) idx = csr_src[base + lane];
        int cnt = min(32, end - base);
        for (int j = 0; j < cnt; ++j) {
            int s = __shfl(idx, j, 32);
            float4 u = bf2f4(H[s * 32 + lane]);
            if (bn) {
                u.x = fmaxf(sa.x * u.x + sb.x, 0.f);
                u.y = fmaxf(sa.y * u.y + sb.y, 0.f);
                u.z = fmaxf(sa.z * u.z + sb.z, 0.f);
                u.w = fmaxf(sa.w * u.w + sb.w, 0.f);
            }
            acc.x += u.x; acc.y += u.y; acc.z += u.z; acc.w += u.w;
        }
    }
    A[node * 32 + lane] = make_ushort4(f2bf(acc.x), f2bf(acc.y),
                                       f2bf(acc.z), f2bf(acc.w));
}

// ===========================================================================
// Fused MLP:  z2 = (relu(A @ W1 + b1)) @ W2 + b2  via bf16 MFMA 16x16x32.
// A bf16 [M,128]; Wt* bf16-bits [128(n),128(k)]; Hout bf16 [M,128].
// Block 256 = 4 waves; wave computes 16 rows x 128 cols for BOTH GEMMs.
// z1 is re-laid out C-layout -> A-layout via a per-wave LDS tile (16 x LSTR).
// A-frag: lane(m=lane&15, q=lane>>4), frag kk holds A[m][kk*32+q*8 .. +7].
// C/D: col = ct*16 + (lane&15), row = q*4 + reg.
// Optional per-column sum/sumsq (BN stats) on fp32 z2.  M % 16 == 0.
// ===========================================================================
__global__ __launch_bounds__(256) void mlp_fused_kernel(
    const ushort* __restrict__ A,
    const short* __restrict__ Wt1,
    const short* __restrict__ Wt2,
    const float* __restrict__ bias1,
    const float* __restrict__ bias2,
    ushort* __restrict__ Hout,
    float* __restrict__ statsSum,
    float* __restrict__ statsSq,
    int M)
{
    __shared__ float ssum[128];
    __shared__ float ssq[128];
    __shared__ __align__(16) short zlds[4][16 * LSTR];

    const int tid  = threadIdx.x;
    const int wv   = tid >> 6;
    const int lane = tid & 63;
    const int q    = lane >> 4;
    const int mrow = lane & 15;
    const int row0 = blockIdx.x * 64 + wv * 16;
    const bool doStats = (statsSum != nullptr);
    const bool active = (row0 < M);
    if (doStats && tid < 128) { ssum[tid] = 0.f; ssq[tid] = 0.f; }

    short* zw = &zlds[wv][0];

    // ---- GEMM1: z1 = relu(A@W1 + b1) -> LDS (bf16, A-layout-ready) ----
    if (active) {
        f32x4 acc[8];
        #pragma unroll
        for (int ct = 0; ct < 8; ++ct) acc[ct] = (f32x4){0.f, 0.f, 0.f, 0.f};
        bfrag8 af[4];
        const bfrag8* A8 = (const bfrag8*)(A + (size_t)(row0 + mrow) * 128);
        #pragma unroll
        for (int kk = 0; kk < 4; ++kk) af[kk] = A8[kk * 4 + q];
        const bfrag8* W18 = (const bfrag8*)Wt1;
        #pragma unroll
        for (int kk = 0; kk < 4; ++kk) {
            #pragma unroll
            for (int ct = 0; ct < 8; ++ct) {
                acc[ct] = __builtin_amdgcn_mfma_f32_16x16x32_bf16(
                    af[kk], W18[(ct * 16 + mrow) * 16 + kk * 4 + q], acc[ct], 0, 0, 0);
            }
        }
        #pragma unroll
        for (int ct = 0; ct < 8; ++ct) {
            int col = ct * 16 + mrow;
            float bv = bias1[col];
            #pragma unroll
            for (int r = 0; r < 4; ++r) {
                float v = fmaxf(acc[ct][r] + bv, 0.f);
                zw[(q * 4 + r) * LSTR + col] = (short)f2bf(v);
            }
        }
    }
    __syncthreads();

    // ---- GEMM2: z2 = z1 @ W2 + b2 ----
    if (active) {
        f32x4 acc2[8];
        #pragma unroll
        for (int ct = 0; ct < 8; ++ct) acc2[ct] = (f32x4){0.f, 0.f, 0.f, 0.f};
        bfrag8 a2[4];
        #pragma unroll
        for (int kk = 0; kk < 4; ++kk)
            a2[kk] = *(const bfrag8*)(zw + mrow * LSTR + kk * 32 + q * 8);
        const bfrag8* W28 = (const bfrag8*)Wt2;
        #pragma unroll
        for (int kk = 0; kk < 4; ++kk) {
            #pragma unroll
            for (int ct = 0; ct < 8; ++ct) {
                acc2[ct] = __builtin_amdgcn_mfma_f32_16x16x32_bf16(
                    a2[kk], W28[(ct * 16 + mrow) * 16 + kk * 4 + q], acc2[ct], 0, 0, 0);
            }
        }
        // ---- epilogue: bias, store bf16, BN stats on fp32 values ----
        #pragma unroll
        for (int ct = 0; ct < 8; ++ct) {
            int col = ct * 16 + mrow;
            float bv = bias2[col];
            float s = 0.f, sq = 0.f;
            #pragma unroll
            for (int r = 0; r < 4; ++r) {
                float v = acc2[ct][r] + bv;
                Hout[(size_t)(row0 + q * 4 + r) * 128 + col] = f2bf(v);
                s += v; sq += v * v;
            }
            if (doStats) {
                s  += __shfl_xor(s, 16);  s  += __shfl_xor(s, 32);
                sq += __shfl_xor(sq, 16); sq += __shfl_xor(sq, 32);
                if (q == 0) {
                    atomicAdd(&ssum[col], s);
                    atomicAdd(&ssq[col], sq);
                }
            }
        }
    }
    if (doStats) {
        __syncthreads();
        if (tid < 128) {
            atomicAdd(&statsSum[tid], ssum[tid]);
            atomicAdd(&statsSq[tid],  ssq[tid]);
        }
    }
}

// ===========================================================================
// BN stats -> per-column scale/bias
// ===========================================================================
__global__ void bnscale_kernel(
    const float* __restrict__ sum, const float* __restrict__ sq,
    const float* __restrict__ gamma, const float* __restrict__ beta,
    float* __restrict__ a, float* __restrict__ b)
{
    int c = threadIdx.x;
    float invN = 1.0f / (float)N_NODES;
    float mu = sum[c] * invN;
    float var = sq[c] * invN - mu * mu;
    float ai = gamma[c] * rsqrtf(var + 1e-5f);
    a[c] = ai;
    b[c] = beta[c] - mu * ai;
}

// ===========================================================================
// global_add_pool (bf16 in): batch sorted -> run-length accumulate.
// ===========================================================================
__global__ __launch_bounds__(256) void pool_kernel(
    const ushort4* __restrict__ H, const int* __restrict__ batch,
    float* __restrict__ out)
{
    int c4 = threadIdx.x & 31;
    int nl = threadIdx.x >> 5;
    int node0 = blockIdx.x * 256;
    float4 acc = f4zero();
    int gcur = -1;
    for (int i = nl; i < 256; i += 8) {
        int n = node0 + i;
        if (n >= N_NODES) break;
        int g = batch[n];
        if (g != gcur) {
            if (gcur >= 0) {
                float* o = out + gcur * D + c4 * 4;
                atomicAdd(o + 0, acc.x); atomicAdd(o + 1, acc.y);
                atomicAdd(o + 2, acc.z); atomicAdd(o + 3, acc.w);
            }
            gcur = g;
            acc = f4zero();
        }
        float4 v = bf2f4(H[n * 32 + c4]);
        acc.x += v.x; acc.y += v.y; acc.z += v.z; acc.w += v.w;
    }
    if (gcur >= 0) {
        float* o = out + gcur * D + c4 * 4;
        atomicAdd(o + 0, acc.x); atomicAdd(o + 1, acc.y);
        atomicAdd(o + 2, acc.z); atomicAdd(o + 3, acc.w);
    }
}

extern "C" void kernel_launch(void* const* d_in, const int* in_sizes, int n_in,
                              void* d_out, int out_size, void* d_ws, size_t ws_size,
                              hipStream_t stream)
{
    const float* x     = (const float*)d_in[0];
    const int*   ei    = (const int*)d_in[1];
    const int*   batch = (const int*)d_in[2];
    const float* W1    = (const float*)d_in[3];
    const float* b1    = (const float*)d_in[4];
    const float* W2    = (const float*)d_in[5];
    const float* b2    = (const float*)d_in[6];
    const float* eps   = (const float*)d_in[7];
    const float* gamma = (const float*)d_in[8];
    const float* beta  = (const float*)d_in[9];
    float* out = (float*)d_out;

    // ---- workspace layout ----
    unsigned short* Abf = (unsigned short*)d_ws;          // [N,128] bf16
    unsigned short* Hbf = Abf + (size_t)N_NODES * D;      // [N,128] bf16
    float* statsSum = (float*)(Hbf + (size_t)N_NODES * D);// [D]
    float* statsSq  = statsSum + D;                       // [D]
    float* abn      = statsSq + D;                        // [D]
    float* bbn      = abn + D;                            // [D]
    int*   deg      = (int*)(bbn + D);                    // [N]
    int*   cursor   = deg + N_NODES;                      // [N]
    int*   row_ptr  = cursor + N_NODES;                   // [N+1]
    int*   blockSum = row_ptr + N_NODES + 1;              // [256]
    int*   csr_src  = blockSum + 256;                     // [E]
    short* Wt       = (short*)(csr_src + N_EDGES);        // [8][128][128]

    const int* src = ei;
    const int* dst = ei + N_EDGES;

    dim3 blk(256);
    const int gemmBlocks   = (N_NODES + 63) / 64;        // 782
    const int edgeBlocks   = (N_EDGES + 255) / 256;      // 3125
    const int gatherBlocks = (N_NODES + 7) / 8;          // 6250
    const int scanBlocks   = (N_NODES + 255) / 256;      // 196
    const int convBlocks   = (N_NODES * 32 + 255) / 256; // 6250

    // ---- one-time prep: CSR + W/x conversion ----
    hipMemsetAsync(deg, 0, (size_t)(2 * N_NODES) * sizeof(int), stream);
    hist_kernel<<<edgeBlocks, blk, 0, stream>>>(dst, deg);
    wconv_kernel<<<512, blk, 0, stream>>>(W1, W2, Wt);
    xconv_kernel<<<convBlocks, blk, 0, stream>>>((const float4*)x, (ushort4*)Hbf);
    scan_block_kernel<<<scanBlocks, blk, 0, stream>>>(deg, row_ptr, blockSum);
    scan_top_kernel<<<1, blk, 0, stream>>>(blockSum, scanBlocks);
    scan_add_kernel<<<scanBlocks, blk, 0, stream>>>(blockSum, row_ptr);
    fill_kernel<<<edgeBlocks, blk, 0, stream>>>(src, dst, row_ptr, cursor, csr_src);

    for (int layer = 0; layer < 4; ++layer) {
        const float* a = (layer == 0) ? nullptr : abn;
        const float* b = (layer == 0) ? nullptr : bbn;
        const bool bn = (layer < 3);
        // A = (1+eps)*y(h) + sum y(h_nb)   (y = prev BN+ReLU, fused)
        gather_kernel<<<gatherBlocks, blk, 0, stream>>>(
            (const ushort4*)Hbf, row_ptr, csr_src, a, b, eps + layer,
            (ushort4*)Abf);
        if (bn) hipMemsetAsync(statsSum, 0, 2 * D * sizeof(float), stream);
        // z2 = relu(A@W1+b1)@W2 + b2 -> Hbf (+ BN stats)
        mlp_fused_kernel<<<gemmBlocks, blk, 0, stream>>>(
            Abf, Wt + (size_t)layer * 16384, Wt + (size_t)(4 + layer) * 16384,
            b1 + (size_t)layer * D, b2 + (size_t)layer * D, Hbf,
            bn ? statsSum : nullptr, bn ? statsSq : nullptr, N_NODES);
        if (bn) bnscale_kernel<<<1, 128, 0, stream>>>(
            statsSum, statsSq, gamma + (size_t)layer * D, beta + (size_t)layer * D,
            abn, bbn);
    }

    hipMemsetAsync(out, 0, (size_t)NUM_GRAPHS * D * sizeof(float), stream);
    pool_kernel<<<scanBlocks, blk, 0, stream>>>(
        (const ushort4*)Hbf, batch, out);
}

// Round 6
// 454.302 us; speedup vs baseline: 14.9809x; 1.2329x over previous
//
#include <hip/hip_runtime.h>

#define N_NODES 50000
#define N_EDGES 800000
#define D 128
#define NUM_GRAPHS 128

typedef __attribute__((ext_vector_type(8)))  short bfrag8;
typedef __attribute__((ext_vector_type(16))) float f32x16;

__device__ __forceinline__ float4 f4zero() { return make_float4(0.f, 0.f, 0.f, 0.f); }

// fp32 -> bf16 bits, round-to-nearest-even
__device__ __forceinline__ unsigned short f2bf(float f) {
    unsigned u = __float_as_uint(f);
    unsigned r = (u + 0x7fffu + ((u >> 16) & 1u)) >> 16;
    return (unsigned short)r;
}
__device__ __forceinline__ float bf2f(unsigned short b) {
    return __uint_as_float(((unsigned)b) << 16);
}
__device__ __forceinline__ float4 bf2f4(ushort4 u) {
    return make_float4(bf2f(u.x), bf2f(u.y), bf2f(u.z), bf2f(u.w));
}
__device__ __forceinline__ float4 bnrelu(float4 v, float4 a, float4 b) {
    v.x = fmaxf(a.x * v.x + b.x, 0.f);
    v.y = fmaxf(a.y * v.y + b.y, 0.f);
    v.z = fmaxf(a.z * v.z + b.z, 0.f);
    v.w = fmaxf(a.w * v.w + b.w, 0.f);
    return v;
}

// ===========================================================================
// CSR build
// ===========================================================================
__global__ __launch_bounds__(256) void hist_kernel(
    const int* __restrict__ dst, int* __restrict__ deg)
{
    int e = blockIdx.x * 256 + threadIdx.x;
    if (e < N_EDGES) atomicAdd(&deg[dst[e]], 1);
}

__global__ __launch_bounds__(256) void scan_block_kernel(
    const int* __restrict__ deg, int* __restrict__ row_ptr,
    int* __restrict__ blockSum)
{
    __shared__ int wsum[4];
    int t = threadIdx.x, b = blockIdx.x;
    int i = b * 256 + t;
    int v = (i < N_NODES) ? deg[i] : 0;
    int lane = t & 63, wid = t >> 6;
    #pragma unroll
    for (int off = 1; off < 64; off <<= 1) {
        int u = __shfl_up(v, off, 64);
        if (lane >= off) v += u;
    }
    if (lane == 63) wsum[wid] = v;
    __syncthreads();
    int add = 0;
    for (int w = 0; w < wid; ++w) add += wsum[w];
    v += add;
    if (i < N_NODES) row_ptr[i + 1] = v;
    if (t == 255) blockSum[b] = v;
}

__global__ __launch_bounds__(256) void scan_top_kernel(int* blockSum, int nb)
{
    __shared__ int wsum[4];
    int t = threadIdx.x;
    int v = (t < nb) ? blockSum[t] : 0;
    int lane = t & 63, wid = t >> 6;
    #pragma unroll
    for (int off = 1; off < 64; off <<= 1) {
        int u = __shfl_up(v, off, 64);
        if (lane >= off) v += u;
    }
    if (lane == 63) wsum[wid] = v;
    __syncthreads();
    int add = 0;
    for (int w = 0; w < wid; ++w) add += wsum[w];
    v += add;
    if (t < nb) blockSum[t] = v;
}

__global__ __launch_bounds__(256) void scan_add_kernel(
    const int* __restrict__ blockSum, int* __restrict__ row_ptr)
{
    int t = threadIdx.x, b = blockIdx.x;
    int i = b * 256 + t;
    if (b > 0 && i < N_NODES) row_ptr[i + 1] += blockSum[b - 1];
    if (i == 0) row_ptr[0] = 0;
}

__global__ __launch_bounds__(256) void fill_kernel(
    const int* __restrict__ src, const int* __restrict__ dst,
    const int* __restrict__ row_ptr, int* __restrict__ cursor,
    int* __restrict__ csr_src)
{
    int e = blockIdx.x * 256 + threadIdx.x;
    if (e >= N_EDGES) return;
    int d = dst[e];
    int pos = atomicAdd(&cursor[d], 1);
    csr_src[row_ptr[d] + pos] = src[e];
}

// ===========================================================================
// W[k][n] fp32 -> Wt[n][k] bf16 bits, 8 matrices (W1[0..3], W2[0..3])
// ===========================================================================
__global__ __launch_bounds__(256) void wconv_kernel(
    const float* __restrict__ W1, const float* __restrict__ W2,
    short* __restrict__ Wt)
{
    int idx = blockIdx.x * 256 + threadIdx.x;     // 0 .. 8*16384-1
    int m = idx >> 14;
    int rem = idx & 16383;
    int k = rem >> 7;
    int n = rem & 127;
    const float* W = (m < 4) ? (W1 + (size_t)m * 16384)
                             : (W2 + (size_t)(m - 4) * 16384);
    Wt[(size_t)m * 16384 + n * 128 + k] = (short)f2bf(W[k * 128 + n]);
}

// x fp32 -> bf16 bits
__global__ __launch_bounds__(256) void xconv_kernel(
    const float4* __restrict__ x4, ushort4* __restrict__ o)
{
    int i = blockIdx.x * 256 + threadIdx.x;      // N*32 float4s
    if (i >= N_NODES * 32) return;
    float4 v = x4[i];
    o[i] = make_ushort4(f2bf(v.x), f2bf(v.y), f2bf(v.z), f2bf(v.w));
}

// ===========================================================================
// Fused gather (bf16 in/out), 4-way unrolled neighbor loop for MLP:
//   A[n] = bf16( (1+eps)*y(h[n]) + sum_{j in N(n)} y(h[j]) )
// y(v) = relu(a*v + b) if BN params given (prev layer's BN), else v.
// ===========================================================================
__global__ __launch_bounds__(256) void gather_kernel(
    const ushort4* __restrict__ H, const int* __restrict__ row_ptr,
    const int* __restrict__ csr_src, const float* __restrict__ abn,
    const float* __restrict__ bbn, const float* __restrict__ epsp,
    ushort4* __restrict__ A)
{
    int node = blockIdx.x * 8 + (threadIdx.x >> 5);
    if (node >= N_NODES) return;
    int lane = threadIdx.x & 31;
    const bool bn = (abn != nullptr);
    float4 sa = make_float4(1.f, 1.f, 1.f, 1.f);
    float4 sb = f4zero();
    if (bn) { sa = ((const float4*)abn)[lane]; sb = ((const float4*)bbn)[lane]; }
    float eps1 = 1.0f + *epsp;
    int beg = row_ptr[node], end = row_ptr[node + 1];

    float4 v = bf2f4(H[node * 32 + lane]);
    if (bn) v = bnrelu(v, sa, sb);
    float4 a0 = make_float4(eps1 * v.x, eps1 * v.y, eps1 * v.z, eps1 * v.w);
    float4 a1 = f4zero(), a2 = f4zero(), a3 = f4zero();

    for (int base = beg; base < end; base += 32) {
        int idx = 0;
        if (base + lane < end) idx = csr_src[base + lane];
        int cnt = min(32, end - base);
        int j = 0;
        for (; j + 4 <= cnt; j += 4) {
            int s0 = __shfl(idx, j + 0, 32);
            int s1 = __shfl(idx, j + 1, 32);
            int s2 = __shfl(idx, j + 2, 32);
            int s3 = __shfl(idx, j + 3, 32);
            float4 u0 = bf2f4(H[s0 * 32 + lane]);
            float4 u1 = bf2f4(H[s1 * 32 + lane]);
            float4 u2 = bf2f4(H[s2 * 32 + lane]);
            float4 u3 = bf2f4(H[s3 * 32 + lane]);
            if (bn) {
                u0 = bnrelu(u0, sa, sb); u1 = bnrelu(u1, sa, sb);
                u2 = bnrelu(u2, sa, sb); u3 = bnrelu(u3, sa, sb);
            }
            a0.x += u0.x; a0.y += u0.y; a0.z += u0.z; a0.w += u0.w;
            a1.x += u1.x; a1.y += u1.y; a1.z += u1.z; a1.w += u1.w;
            a2.x += u2.x; a2.y += u2.y; a2.z += u2.z; a2.w += u2.w;
            a3.x += u3.x; a3.y += u3.y; a3.z += u3.z; a3.w += u3.w;
        }
        for (; j < cnt; ++j) {
            int s = __shfl(idx, j, 32);
            float4 u = bf2f4(H[s * 32 + lane]);
            if (bn) u = bnrelu(u, sa, sb);
            a0.x += u.x; a0.y += u.y; a0.z += u.z; a0.w += u.w;
        }
    }
    a0.x += a1.x + a2.x + a3.x;
    a0.y += a1.y + a2.y + a3.y;
    a0.z += a1.z + a2.z + a3.z;
    a0.w += a1.w + a2.w + a3.w;
    A[node * 32 + lane] = make_ushort4(f2bf(a0.x), f2bf(a0.y),
                                       f2bf(a0.z), f2bf(a0.w));
}

// ===========================================================================
// Fused MLP:  z2 = (relu(A @ W1 + b1)) @ W2 + b2  via bf16 MFMA 32x32x16.
// Block = 128 thr = 2 waves; wave computes 32 rows x 128 cols for both GEMMs.
// W1/W2 staged to LDS (32KB, reused) with XOR-chunk swizzle (conflict-free
// ds_read_b128 B-fragments). z1 and z2 round-trip through a swizzled
// per-wave LDS tile (C-layout -> A-layout / coalesced stores).
// A-frag (32x32x16): lane holds A[m=lane&31][kk*16 + (lane>>5)*8 + 0..7].
// B-frag: lane holds Wt[n=ct*32+(lane&31)][kk*16 + (lane>>5)*8 + 0..7].
// C/D: col = ct*32+(lane&31), row = (reg&3) + 8*(reg>>2) + 4*(lane>>5).
// ===========================================================================
__global__ __launch_bounds__(128, 2) void mlp_fused_kernel(
    const ushort* __restrict__ A,
    const short* __restrict__ Wt1,
    const short* __restrict__ Wt2,
    const float* __restrict__ bias1,
    const float* __restrict__ bias2,
    ushort* __restrict__ Hout,
    float* __restrict__ statsSum,
    float* __restrict__ statsSq,
    int M)
{
    __shared__ __align__(16) short Wlds[128 * 128];   // 32 KB
    __shared__ __align__(16) short zlds[2][32 * 128]; // 2 x 8 KB
    __shared__ float ssum[128];
    __shared__ float ssq[128];

    const int tid  = threadIdx.x;
    const int wv   = tid >> 6;
    const int lane = tid & 63;
    const int half = lane >> 5;
    const int ln   = lane & 31;
    const int row0 = blockIdx.x * 64 + wv * 32;
    const bool doStats = (statsSum != nullptr);
    if (doStats) { ssum[tid] = 0.f; ssq[tid] = 0.f; }

    short* zw = &zlds[wv][0];

    // ---- stage W1 -> Wlds (swizzled: chunk c of row n at c^(n&15)) ----
    {
        const int4* Wg = (const int4*)Wt1;
        int4* Wl = (int4*)Wlds;
        #pragma unroll
        for (int i = 0; i < 16; ++i) {
            int id = i * 128 + tid;           // 0..2047: n=id>>4, c=id&15
            int n = id >> 4, c = id & 15;
            Wl[n * 16 + (c ^ (n & 15))] = Wg[id];
        }
    }
    __syncthreads();

    // ---- GEMM1: z1 = relu(A@W1 + b1) -> zlds (swizzled A-layout) ----
    {
        f32x16 acc[4];
        #pragma unroll
        for (int ct = 0; ct < 4; ++ct)
            #pragma unroll
            for (int r = 0; r < 16; ++r) acc[ct][r] = 0.f;

        bfrag8 af[8];
        int rowc = min(row0 + ln, M - 1);
        const ushort* ap = A + (size_t)rowc * 128 + half * 8;
        #pragma unroll
        for (int kk = 0; kk < 8; ++kk)
            af[kk] = *(const bfrag8*)(ap + kk * 16);

        #pragma unroll
        for (int kk = 0; kk < 8; ++kk) {
            int c = kk * 2 + half;
            #pragma unroll
            for (int ct = 0; ct < 4; ++ct) {
                int n = ct * 32 + ln;
                bfrag8 bf = *(const bfrag8*)(Wlds + n * 128 + ((c ^ (n & 15)) << 3));
                acc[ct] = __builtin_amdgcn_mfma_f32_32x32x16_bf16(
                    af[kk], bf, acc[ct], 0, 0, 0);
            }
        }
        #pragma unroll
        for (int ct = 0; ct < 4; ++ct) {
            int col = ct * 32 + ln;
            int cc = col >> 3, co = col & 7;
            float bv = bias1[col];
            #pragma unroll
            for (int r = 0; r < 16; ++r) {
                int rloc = (r & 3) + 8 * (r >> 2) + 4 * half;
                float v = fmaxf(acc[ct][r] + bv, 0.f);
                zw[rloc * 128 + ((cc ^ (rloc & 15)) << 3) + co] = (short)f2bf(v);
            }
        }
    }
    __syncthreads();

    // ---- stage W2 -> Wlds ----
    {
        const int4* Wg = (const int4*)Wt2;
        int4* Wl = (int4*)Wlds;
        #pragma unroll
        for (int i = 0; i < 16; ++i) {
            int id = i * 128 + tid;
            int n = id >> 4, c = id & 15;
            Wl[n * 16 + (c ^ (n & 15))] = Wg[id];
        }
    }
    __syncthreads();

    // ---- GEMM2: z2 = z1 @ W2 + b2 ----
    {
        f32x16 acc[4];
        #pragma unroll
        for (int ct = 0; ct < 4; ++ct)
            #pragma unroll
            for (int r = 0; r < 16; ++r) acc[ct][r] = 0.f;

        bfrag8 af[8];
        #pragma unroll
        for (int kk = 0; kk < 8; ++kk) {
            int c = kk * 2 + half;
            af[kk] = *(const bfrag8*)(zw + ln * 128 + ((c ^ (ln & 15)) << 3));
        }
        #pragma unroll
        for (int kk = 0; kk < 8; ++kk) {
            int c = kk * 2 + half;
            #pragma unroll
            for (int ct = 0; ct < 4; ++ct) {
                int n = ct * 32 + ln;
                bfrag8 bf = *(const bfrag8*)(Wlds + n * 128 + ((c ^ (n & 15)) << 3));
                acc[ct] = __builtin_amdgcn_mfma_f32_32x32x16_bf16(
                    af[kk], bf, acc[ct], 0, 0, 0);
            }
        }
        // epilogue: bias, stats, write z2 (bf16) to zlds for coalesced store
        #pragma unroll
        for (int ct = 0; ct < 4; ++ct) {
            int col = ct * 32 + ln;
            int cc = col >> 3, co = col & 7;
            float bv = bias2[col];
            float s = 0.f, sq = 0.f;
            #pragma unroll
            for (int r = 0; r < 16; ++r) {
                int rloc = (r & 3) + 8 * (r >> 2) + 4 * half;
                float v = acc[ct][r] + bv;
                zw[rloc * 128 + ((cc ^ (rloc & 15)) << 3) + co] = (short)f2bf(v);
                if (row0 + rloc < M) { s += v; sq += v * v; }
            }
            if (doStats) {
                s  += __shfl_xor(s, 32);
                sq += __shfl_xor(sq, 32);
                if (half == 0) {
                    atomicAdd(&ssum[col], s);
                    atomicAdd(&ssq[col], sq);
                }
            }
        }
    }
    __syncthreads();

    // ---- coalesced store: zlds -> Hout ----
    {
        const int4* zl = (const int4*)zw;
        int4* Ho = (int4*)Hout;
        #pragma unroll
        for (int i = 0; i < 8; ++i) {
            int id = i * 64 + lane;           // 0..511: row=id>>4, c=id&15
            int r = id >> 4, c = id & 15;
            int grow = row0 + r;
            if (grow < M)
                Ho[(size_t)grow * 16 + c] = zl[r * 16 + (c ^ (r & 15))];
        }
    }
    if (doStats) {
        atomicAdd(&statsSum[tid], ssum[tid]);
        atomicAdd(&statsSq[tid],  ssq[tid]);
    }
}

// ===========================================================================
// BN stats -> per-column scale/bias
// ===========================================================================
__global__ void bnscale_kernel(
    const float* __restrict__ sum, const float* __restrict__ sq,
    const float* __restrict__ gamma, const float* __restrict__ beta,
    float* __restrict__ a, float* __restrict__ b)
{
    int c = threadIdx.x;
    float invN = 1.0f / (float)N_NODES;
    float mu = sum[c] * invN;
    float var = sq[c] * invN - mu * mu;
    float ai = gamma[c] * rsqrtf(var + 1e-5f);
    a[c] = ai;
    b[c] = beta[c] - mu * ai;
}

// ===========================================================================
// global_add_pool (bf16 in): batch sorted -> run-length accumulate.
// ===========================================================================
__global__ __launch_bounds__(256) void pool_kernel(
    const ushort4* __restrict__ H, const int* __restrict__ batch,
    float* __restrict__ out)
{
    int c4 = threadIdx.x & 31;
    int nl = threadIdx.x >> 5;
    int node0 = blockIdx.x * 256;
    float4 acc = f4zero();
    int gcur = -1;
    for (int i = nl; i < 256; i += 8) {
        int n = node0 + i;
        if (n >= N_NODES) break;
        int g = batch[n];
        if (g != gcur) {
            if (gcur >= 0) {
                float* o = out + gcur * D + c4 * 4;
                atomicAdd(o + 0, acc.x); atomicAdd(o + 1, acc.y);
                atomicAdd(o + 2, acc.z); atomicAdd(o + 3, acc.w);
            }
            gcur = g;
            acc = f4zero();
        }
        float4 v = bf2f4(H[n * 32 + c4]);
        acc.x += v.x; acc.y += v.y; acc.z += v.z; acc.w += v.w;
    }
    if (gcur >= 0) {
        float* o = out + gcur * D + c4 * 4;
        atomicAdd(o + 0, acc.x); atomicAdd(o + 1, acc.y);
        atomicAdd(o + 2, acc.z); atomicAdd(o + 3, acc.w);
    }
}

extern "C" void kernel_launch(void* const* d_in, const int* in_sizes, int n_in,
                              void* d_out, int out_size, void* d_ws, size_t ws_size,
                              hipStream_t stream)
{
    const float* x     = (const float*)d_in[0];
    const int*   ei    = (const int*)d_in[1];
    const int*   batch = (const int*)d_in[2];
    const float* W1    = (const float*)d_in[3];
    const float* b1    = (const float*)d_in[4];
    const float* W2    = (const float*)d_in[5];
    const float* b2    = (const float*)d_in[6];
    const float* eps   = (const float*)d_in[7];
    const float* gamma = (const float*)d_in[8];
    const float* beta  = (const float*)d_in[9];
    float* out = (float*)d_out;

    // ---- workspace layout ----
    unsigned short* Abf = (unsigned short*)d_ws;          // [N,128] bf16
    unsigned short* Hbf = Abf + (size_t)N_NODES * D;      // [N,128] bf16
    float* statsSum = (float*)(Hbf + (size_t)N_NODES * D);// [D]
    float* statsSq  = statsSum + D;                       // [D]
    float* abn      = statsSq + D;                        // [D]
    float* bbn      = abn + D;                            // [D]
    int*   deg      = (int*)(bbn + D);                    // [N]
    int*   cursor   = deg + N_NODES;                      // [N]
    int*   row_ptr  = cursor + N_NODES;                   // [N+1]
    int*   blockSum = row_ptr + N_NODES + 1;              // [256]
    int*   csr_src  = blockSum + 256;                     // [E]
    short* Wt       = (short*)(csr_src + N_EDGES);        // [8][128][128]

    const int* src = ei;
    const int* dst = ei + N_EDGES;

    dim3 blk(256);
    const int gemmBlocks   = (N_NODES + 63) / 64;        // 782
    const int edgeBlocks   = (N_EDGES + 255) / 256;      // 3125
    const int gatherBlocks = (N_NODES + 7) / 8;          // 6250
    const int scanBlocks   = (N_NODES + 255) / 256;      // 196
    const int convBlocks   = (N_NODES * 32 + 255) / 256; // 6250

    // ---- one-time prep: CSR + W/x conversion ----
    hipMemsetAsync(deg, 0, (size_t)(2 * N_NODES) * sizeof(int), stream);
    hist_kernel<<<edgeBlocks, blk, 0, stream>>>(dst, deg);
    wconv_kernel<<<512, blk, 0, stream>>>(W1, W2, Wt);
    xconv_kernel<<<convBlocks, blk, 0, stream>>>((const float4*)x, (ushort4*)Hbf);
    scan_block_kernel<<<scanBlocks, blk, 0, stream>>>(deg, row_ptr, blockSum);
    scan_top_kernel<<<1, blk, 0, stream>>>(blockSum, scanBlocks);
    scan_add_kernel<<<scanBlocks, blk, 0, stream>>>(blockSum, row_ptr);
    fill_kernel<<<edgeBlocks, blk, 0, stream>>>(src, dst, row_ptr, cursor, csr_src);

    for (int layer = 0; layer < 4; ++layer) {
        const float* a = (layer == 0) ? nullptr : abn;
        const float* b = (layer == 0) ? nullptr : bbn;
        const bool bn = (layer < 3);
        // A = (1+eps)*y(h) + sum y(h_nb)   (y = prev BN+ReLU, fused)
        gather_kernel<<<gatherBlocks, blk, 0, stream>>>(
            (const ushort4*)Hbf, row_ptr, csr_src, a, b, eps + layer,
            (ushort4*)Abf);
        if (bn) hipMemsetAsync(statsSum, 0, 2 * D * sizeof(float), stream);
        // z2 = relu(A@W1+b1)@W2 + b2 -> Hbf (+ BN stats)
        mlp_fused_kernel<<<gemmBlocks, dim3(128), 0, stream>>>(
            Abf, Wt + (size_t)layer * 16384, Wt + (size_t)(4 + layer) * 16384,
            b1 + (size_t)layer * D, b2 + (size_t)layer * D, Hbf,
            bn ? statsSum : nullptr, bn ? statsSq : nullptr, N_NODES);
        if (bn) bnscale_kernel<<<1, 128, 0, stream>>>(
            statsSum, statsSq, gamma + (size_t)layer * D, beta + (size_t)layer * D,
            abn, bbn);
    }

    hipMemsetAsync(out, 0, (size_t)NUM_GRAPHS * D * sizeof(float), stream);
    pool_kernel<<<scanBlocks, blk, 0, stream>>>(
        (const ushort4*)Hbf, batch, out);
}